// Round 13
// baseline (7414.261 us; speedup 1.0000x reference)
//
#include <hip/hip_runtime.h>
#include <hip/hip_bf16.h>
#include <math.h>

typedef unsigned short u16;
typedef __attribute__((ext_vector_type(4))) float f32x4;
typedef __attribute__((ext_vector_type(8))) short s16x8;

#define BB  512
#define TT  120
#define LAT 292
#define HH1 701
#define HH3 901
#define H1P 704
#define H3P 960
#define CH  35
#define NSTEP (TT + 3)

// ws layout (bytes)
static const size_t O_X    = 0;
static const size_t O_XP1  = 598016;                // 512*2112*4 f32
static const size_t O_H1F  = 4923392;               // 2*512*704*4 f32 carry
static const size_t O_H2F  = 7806976;
static const size_t O_H3F  = 10690560;
static const size_t O_H1B  = 14622720;              // 2-slot bf16 h (fallback)
static const size_t O_H2B  = 16064512;
static const size_t O_H3B  = 17506304;
static const size_t O_WHT1 = 19472384;
static const size_t O_WIT2 = 22446080;
static const size_t O_WHT2 = 25419776;
static const size_t O_WIT3 = 28393472;
static const size_t O_WHT3 = 32358400;
static const size_t O_WOT  = 37765120;
static const size_t O_TAB  = 37888000;              // 256*4
static const size_t O_CNT  = 37889024;              // NSTEP*4
static const size_t ZERO_SMALL = 14548992;          // O_H1F..O_H3B end
static const size_t RING_BASE  = 37900288;
static const size_t S1B = (size_t)BB * H1P * 2;     // 720896
static const size_t S3B = (size_t)BB * H3P * 2;     // 983040
static const size_t SLOTALL = S1B + S1B + S3B;      // 2424832

#define DSWZ(row, g) ((((g) ^ ((row) & 7)) << 4))

static __device__ __forceinline__ u16 f2b(float f){
  union { float f; unsigned int i; } v; v.f = f;
  unsigned int x = v.i;
  return (u16)((x + 0x7FFFu + ((x >> 16) & 1u)) >> 16);
}

#define GLL16(g, l) __builtin_amdgcn_global_load_lds( \
    (const __attribute__((address_space(1))) unsigned int*)(g), \
    (__attribute__((address_space(3))) unsigned int*)(l), 16, 0, 0)

static __device__ __forceinline__ void st_u16_sc(u16* p, u16 v) {
  asm volatile("global_store_short %0, %1, off sc0 sc1" :: "v"(p), "v"((unsigned)v) : "memory");
}

// ---------------- prologue kernels ----------------
__launch_bounds__(256)
__global__ void k_selu(const float* __restrict__ z, const float* __restrict__ W1,
                       const float* __restrict__ b1, float* __restrict__ x)
{
  int idx = blockIdx.x * 256 + threadIdx.x;
  if (idx >= BB * LAT) return;
  int b = idx / LAT, i = idx - b * LAT;
  float acc = b1[i];
  const float* zr = z + (size_t)b * LAT;
  for (int k = 0; k < LAT; ++k)
    acc += zr[k] * W1[k * LAT + i];
  const float alpha = 1.6732632423543772f, scale = 1.0507009873554805f;
  x[idx] = scale * (acc > 0.f ? acc : alpha * (expf(acc) - 1.f));
}

__launch_bounds__(256)
__global__ void k_xp1(const float* __restrict__ x, const float* __restrict__ Wi1,
                      const float* __restrict__ bi1, float* __restrict__ xp1)
{
  __shared__ float xs[8][LAT];
  int nb = blockIdx.x % 9, bb = blockIdx.x / 9;
  int n = nb * 256 + threadIdx.x;
  int b0 = bb * 8;
  for (int i = threadIdx.x; i < 8 * LAT; i += 256)
    xs[i / LAT][i % LAT] = x[(size_t)(b0 + i / LAT) * LAT + (i % LAT)];
  __syncthreads();
  if (n >= 2112) return;
  if (n >= 2103) { for (int r = 0; r < 8; ++r) xp1[(size_t)(b0 + r) * 2112 + n] = 0.f; return; }
  float bias = bi1[n];
  float acc[8];
  for (int r = 0; r < 8; ++r) acc[r] = bias;
  for (int k = 0; k < LAT; ++k) {
    float w = Wi1[(size_t)k * 2103 + n];
    #pragma unroll
    for (int r = 0; r < 8; ++r) acc[r] += xs[r][k] * w;
  }
  for (int r = 0; r < 8; ++r) xp1[(size_t)(b0 + r) * 2112 + n] = acc[r];
}

__launch_bounds__(256)
__global__ void k_transpose(const float* __restrict__ W, u16* __restrict__ WT,
                            int K, int N, int Kpad, int RowsPad)
{
  int tilesN = RowsPad / 64;
  int tk = blockIdx.x / tilesN, tn = blockIdx.x % tilesN;
  int k0 = tk * 64, n0 = tn * 64;
  __shared__ u16 lds[64][72];
  int tid = threadIdx.x;
  int nl = tid & 63, q = tid >> 6;
  for (int i = 0; i < 16; ++i) {
    int kl = q * 16 + i;
    int k = k0 + kl, n = n0 + nl;
    lds[kl][nl] = (k < K && n < N) ? f2b(W[(size_t)k * N + n]) : (u16)0;
  }
  __syncthreads();
  for (int i = 0; i < 16; ++i) {
    int rl = q * 16 + i;
    WT[(size_t)(n0 + rl) * Kpad + k0 + nl] = lds[nl][rl];
  }
}

__global__ void k_maketab(unsigned int* __restrict__ tab)
{
  if (threadIdx.x != 0 || blockIdx.x != 0) return;
  for (int x = 0; x < 8; ++x) {
    for (int li = 0; li < 32; ++li) {
      unsigned v;
      if (li < 15) {            // GRU3 ksplit
        int t3 = 15 * x + li;
        v = 0xFFFF0000u | (2u << 12) | ((unsigned)(t3 & 7) << 8) | (unsigned)(t3 >> 3);
      } else if (li < 26) {     // GRU2 ksplit
        int t2 = 11 * x + (li - 15);
        v = 0xFFFF0000u | (1u << 12) | ((unsigned)(t2 & 7) << 8) | (unsigned)(t2 >> 3);
      } else if (li < 31) {     // GRU1 pairs
        int pi = 5 * x + (li - 26);
        int i0 = 2 * pi, i1 = 2 * pi + 1;
        unsigned lo = ((unsigned)(i0 & 7) << 8) | (unsigned)(i0 >> 3);
        unsigned hw = ((unsigned)(i1 & 7) << 8) | (unsigned)(i1 >> 3);
        v = lo | (hw << 16);
      } else {
        if (x < 4) {            // OUT pairs
          unsigned lo = (3u << 12) | ((unsigned)(2 * x) << 8);
          unsigned hw = (3u << 12) | ((unsigned)(2 * x + 1) << 8);
          v = lo | (hw << 16);
        } else {                // leftover GRU1 pairs
          int pi = 40 + (x - 4);
          int i0 = 2 * pi, i1 = 2 * pi + 1;
          unsigned lo = ((unsigned)(i0 & 7) << 8) | (unsigned)(i0 >> 3);
          unsigned hw = ((unsigned)(i1 & 7) << 8) | (unsigned)(i1 >> 3);
          v = lo | (hw << 16);
        }
      }
      tab[x + 8 * li] = v;
    }
  }
}

// ---------------- K=64 staging + MFMA (r9-verbatim, proven 4983us / absmax 3.9e-3) ----------------
static __device__ __forceinline__ void stage_gru(
    const u16* __restrict__ A, int As, const u16* __restrict__ W, int Ws, int WH,
    int r0, int j0, int kbase, int wl, int lane, char* buf)
{
  #pragma unroll
  for (int i = 0; i < 8; ++i) {
    int slot = wl * 512 + i * 64 + lane;
    const u16* g;
    if (slot < 512) {
      int row = slot >> 3, gl = slot & 7;
      int gq = gl ^ (row & 7);
      g = A + (size_t)(r0 + row) * As + kbase + gq * 8;
    } else {
      int s2 = slot - 512;
      int gate = s2 >> 9, loc = s2 & 511;
      int col = loc >> 3, gl = loc & 7;
      int gq = gl ^ (col & 7);
      g = W + ((size_t)gate * WH + j0 + col) * Ws + kbase + gq * 8;
    }
    char* l = buf + (wl * 512 + i * 64) * 16;
    GLL16(g, l);
  }
}

template<int HACC>
static __device__ __forceinline__ void mm_gru(const char* gb, int wr, int wc, int m16, int kg,
                                              f32x4 (&acc)[4][2][2])
{
  #pragma unroll
  for (int s = 0; s < 2; ++s) {
    s16x8 af[2];
    #pragma unroll
    for (int fm = 0; fm < 2; ++fm) {
      int row = wr * 32 + fm * 16 + m16;
      af[fm] = *(const s16x8*)(gb + row * 128 + DSWZ(row, s * 4 + kg));
    }
    #pragma unroll
    for (int g = 0; g < 3; ++g) {
      #pragma unroll
      for (int fn = 0; fn < 2; ++fn) {
        int col = wc * 32 + fn * 16 + m16;
        s16x8 bf = *(const s16x8*)(gb + 8192 + g * 8192 + col * 128 + DSWZ(col, s * 4 + kg));
        const int ai = (g == 2) ? HACC : g;
        #pragma unroll
        for (int fm = 0; fm < 2; ++fm)
          acc[ai][fm][fn] = __builtin_amdgcn_mfma_f32_16x16x32_bf16(af[fm], bf, acc[ai][fm][fn], 0, 0, 0);
      }
    }
  }
}

static __device__ __forceinline__ void gru_pipe(
    const u16* A0, int As0, const u16* W0, int Ws0,
    const u16* A1, int As1, const u16* W1p, int Ws1,
    int WH, int n0, int n1, int k1off,
    int r0, int j0, char* g0, char* g1, int wl, int lane,
    int wr, int wc, int m16, int kg, f32x4 (&acc)[4][2][2])
{
  const int n = n0 + n1;
#define STG(C, BUF) do { int c_ = (C); \
    if (c_ < n0) stage_gru(A0, As0, W0, Ws0, WH, r0, j0, c_ * 64, wl, lane, (BUF)); \
    else         stage_gru(A1, As1, W1p, Ws1, WH, r0, j0, (c_ - n0) * 64 + k1off, wl, lane, (BUF)); \
  } while (0)
  STG(0, g0);
  __syncthreads();
  for (int ch = 0; ch < n; ch += 2) {
    if (ch + 1 < n) STG(ch + 1, g1);
    if (ch < n0) mm_gru<2>(g0, wr, wc, m16, kg, acc);
    else         mm_gru<3>(g0, wr, wc, m16, kg, acc);
    __syncthreads();
    if (ch + 1 >= n) break;
    if (ch + 2 < n) STG(ch + 2, g0);
    if (ch + 1 < n0) mm_gru<2>(g1, wr, wc, m16, kg, acc);
    else             mm_gru<3>(g1, wr, wc, m16, kg, acc);
    __syncthreads();
  }
#undef STG
}

// ---------------- OUT tile (r9-verbatim core) ----------------
static __device__ __forceinline__ void out_tile(
    const u16* __restrict__ Ab, const u16* __restrict__ WoT, const float* __restrict__ bo,
    float* __restrict__ out, int r0, int t,
    char* g0, int ltid, int wr, int wc, int m16, int kg)
{
  f32x4 acc2[2][2];
  { f32x4 z4 = {0.f,0.f,0.f,0.f}; for (int a=0;a<2;++a) for (int b=0;b<2;++b) acc2[a][b]=z4; }
  int4 ra[2], rb2[2];
  const int n = H3P / 64;                 // 15
  #pragma unroll
  for (int it = 0; it < 2; ++it) {
    int gi = it * 256 + ltid; int r = gi >> 3, gq = gi & 7;
    ra[it]  = *(const int4*)(Ab + (size_t)(r0 + r) * H3P + gq * 8);
    rb2[it] = *(const int4*)(WoT + (size_t)r * H3P + gq * 8);
  }
  #pragma unroll
  for (int it = 0; it < 2; ++it) {
    int gi = it * 256 + ltid; int r = gi >> 3, gq = gi & 7;
    *(int4*)(g0 + r * 128 + DSWZ(r, gq)) = ra[it];
    *(int4*)(g0 + 8192 + r * 128 + DSWZ(r, gq)) = rb2[it];
  }
  __syncthreads();
  for (int ch = 0; ch < n; ++ch) {
    const bool have = (ch + 1 < n);
    if (have) {
      int kb = (ch + 1) * 64;
      #pragma unroll
      for (int it = 0; it < 2; ++it) {
        int gi = it * 256 + ltid; int r = gi >> 3, gq = gi & 7;
        ra[it]  = *(const int4*)(Ab + (size_t)(r0 + r) * H3P + kb + gq * 8);
        rb2[it] = *(const int4*)(WoT + (size_t)r * H3P + kb + gq * 8);
      }
    }
    #pragma unroll
    for (int s2 = 0; s2 < 2; ++s2) {
      s16x8 af[2], bf[2];
      #pragma unroll
      for (int fm = 0; fm < 2; ++fm) {
        int row = wr * 32 + fm * 16 + m16;
        af[fm] = *(const s16x8*)(g0 + row * 128 + DSWZ(row, s2 * 4 + kg));
      }
      #pragma unroll
      for (int fn = 0; fn < 2; ++fn) {
        int col = wc * 32 + fn * 16 + m16;
        bf[fn] = *(const s16x8*)(g0 + 8192 + col * 128 + DSWZ(col, s2 * 4 + kg));
      }
      #pragma unroll
      for (int fm = 0; fm < 2; ++fm)
        #pragma unroll
        for (int fn = 0; fn < 2; ++fn)
          acc2[fm][fn] = __builtin_amdgcn_mfma_f32_16x16x32_bf16(af[fm], bf[fn], acc2[fm][fn], 0, 0, 0);
    }
    if (have) {
      __syncthreads();
      #pragma unroll
      for (int it = 0; it < 2; ++it) {
        int gi = it * 256 + ltid; int r = gi >> 3, gq = gi & 7;
        *(int4*)(g0 + r * 128 + DSWZ(r, gq)) = ra[it];
        *(int4*)(g0 + 8192 + r * 128 + DSWZ(r, gq)) = rb2[it];
      }
      __syncthreads();
    }
  }
  __syncthreads();
  float (*ldsL)[68] = (float (*)[68])g0;
  #pragma unroll
  for (int fn = 0; fn < 2; ++fn) {
    int col = wc * 32 + fn * 16 + m16;
    float bov = (col < CH) ? bo[col] : 0.f;
    #pragma unroll
    for (int fm = 0; fm < 2; ++fm)
      #pragma unroll
      for (int ii = 0; ii < 4; ++ii)
        ldsL[wr * 32 + fm * 16 + kg * 4 + ii][col] = acc2[fm][fn][ii] + bov;
  }
  __syncthreads();
  if (ltid < 64) {
    int b = r0 + ltid;
    float mx = -1e30f;
    for (int c2 = 0; c2 < CH; ++c2) mx = fmaxf(mx, ldsL[ltid][c2]);
    float sum = 0.f;
    for (int c2 = 0; c2 < CH; ++c2) sum += expf(ldsL[ltid][c2] - mx);
    float inv = 1.f / sum;
    size_t ob = ((size_t)b * TT + t) * CH;
    for (int c2 = 0; c2 < CH; ++c2) out[ob + c2] = expf(ldsL[ltid][c2] - mx) * inv;
  }
}

// ---------------- fallback kernel: exact r9 per-step launch ----------------
__launch_bounds__(512, 2)
__global__ void k_wave9(int s, const unsigned int* __restrict__ tab,
    const u16* __restrict__ WhT1, const u16* __restrict__ WiT2, const u16* __restrict__ WhT2,
    const u16* __restrict__ WiT3, const u16* __restrict__ WhT3, const u16* __restrict__ WoT,
    const float* __restrict__ xp1,
    const float* __restrict__ gbh1,
    const float* __restrict__ gbi2, const float* __restrict__ gbh2,
    const float* __restrict__ gbi3, const float* __restrict__ gbh3,
    const float* __restrict__ bo,
    float* __restrict__ h1f, u16* __restrict__ h1b,
    float* __restrict__ h2f, u16* __restrict__ h2b,
    float* __restrict__ h3f, u16* __restrict__ h3b,
    float* __restrict__ out)
{
  extern __shared__ __align__(16) char smem[];
  const int tid  = threadIdx.x;
  const int wgrp = tid >> 8;
  const int ltid = tid & 255;
  const int lane = tid & 63;
  const int wl   = (tid >> 6) & 3;
  const int wr = wl >> 1, wc = wl & 1;
  const int m16 = lane & 15, kg = lane >> 4;
  char* g0 = smem + wgrp * 65536;
  char* g1 = g0 + 32768;

  const unsigned e  = tab[blockIdx.x];
  const unsigned lo = e & 0xFFFFu, hi = e >> 16;
  const bool ksplit = (hi == 0xFFFFu);
  const unsigned item = (!ksplit && wgrp == 1) ? hi : lo;
  const int L  = (item >> 12) & 3;
  const int rr = (item >> 8) & 0xF;
  const int cc = item & 0xFF;
  const int t = s - L;
  if (t < 0 || t >= TT) return;
  const int cur = s & 1, prv = cur ^ 1;

  if (L == 3) {
    out_tile(h3b + (size_t)prv * BB * H3P, WoT, bo, out, rr * 64, t, g0, ltid, wr, wc, m16, kg);
    return;
  }

  int H;
  const u16 *A0 = nullptr, *W0 = nullptr, *A1 = nullptr, *W1p = nullptr;
  int As0 = 0, Ws0 = 0, As1 = 0, Ws1 = 0, n0 = 0, n1 = 0, k1off = 0;
  const float *bi = nullptr, *bh;
  float *hfP, *hfC; u16 *hbC;
  if (L == 0) {
    H = HH1;
    A1 = h1b + (size_t)prv * BB * H1P; As1 = H1P; W1p = WhT1; Ws1 = H1P; n1 = 11;
    bh = gbh1;
    hfP = h1f + (size_t)prv * BB * H1P; hfC = h1f + (size_t)cur * BB * H1P;
    hbC = h1b + (size_t)cur * BB * H1P;
  } else if (L == 1) {
    H = HH1; bi = gbi2; bh = gbh2;
    hfP = h2f + (size_t)prv * BB * H1P; hfC = h2f + (size_t)cur * BB * H1P;
    hbC = h2b + (size_t)cur * BB * H1P;
    if (wgrp == 0) { A0 = h1b + (size_t)prv * BB * H1P; As0 = H1P; W0 = WiT2; Ws0 = H1P; n0 = 11; As1 = H1P; }
    else           { A1 = h2b + (size_t)prv * BB * H1P; As1 = H1P; W1p = WhT2; Ws1 = H1P; n1 = 11; }
  } else {
    H = HH3; bi = gbi3; bh = gbh3;
    hfP = h3f + (size_t)prv * BB * H3P; hfC = h3f + (size_t)cur * BB * H3P;
    hbC = h3b + (size_t)cur * BB * H3P;
    if (wgrp == 0) {
      A0 = h2b + (size_t)prv * BB * H1P; As0 = H1P; W0 = WiT3; Ws0 = H1P; n0 = 11;
      A1 = h3b + (size_t)prv * BB * H3P; As1 = H3P; W1p = WhT3; Ws1 = H3P; n1 = 2; k1off = 0;
    } else {
      A1 = h3b + (size_t)prv * BB * H3P; As1 = H3P; W1p = WhT3; Ws1 = H3P; n1 = 13; k1off = 128;
    }
  }
  const int r0 = rr * 64, j0 = cc * 64;

  f32x4 acc[4][2][2];
  { f32x4 z4 = {0.f, 0.f, 0.f, 0.f};
    for (int g = 0; g < 4; ++g) for (int a = 0; a < 2; ++a) for (int b = 0; b < 2; ++b) acc[g][a][b] = z4; }

  gru_pipe(A0, As0, W0, Ws0, A1, As1, W1p, Ws1, H, n0, n1, k1off,
           r0, j0, g0, g1, wl, lane, wr, wc, m16, kg, acc);

  if (ksplit) {
    __syncthreads();
    float* red = (float*)smem;
    if (wgrp == 1) {
      float* b = red + ltid * 64;
      #pragma unroll
      for (int g = 0; g < 4; ++g)
        #pragma unroll
        for (int fm = 0; fm < 2; ++fm)
          #pragma unroll
          for (int fn = 0; fn < 2; ++fn)
            *(f32x4*)(b + ((g * 2 + fm) * 2 + fn) * 4) = acc[g][fm][fn];
    }
    __syncthreads();
    if (wgrp == 1) return;
    {
      const float* b = red + ltid * 64;
      #pragma unroll
      for (int g = 0; g < 4; ++g)
        #pragma unroll
        for (int fm = 0; fm < 2; ++fm)
          #pragma unroll
          for (int fn = 0; fn < 2; ++fn)
            acc[g][fm][fn] += *(const f32x4*)(b + ((g * 2 + fm) * 2 + fn) * 4);
    }
  }

  #pragma unroll
  for (int fn = 0; fn < 2; ++fn) {
    int j = j0 + wc * 32 + fn * 16 + m16;
    if (j >= H) continue;
    float bhz = bh[j], bhr = bh[H + j], bhh = bh[2 * H + j];
    float biz = 0.f, bir = 0.f, bih = 0.f;
    if (L != 0) { biz = bi[j]; bir = bi[H + j]; bih = bi[2 * H + j]; }
    #pragma unroll
    for (int fm = 0; fm < 2; ++fm) {
      #pragma unroll
      for (int ii = 0; ii < 4; ++ii) {
        int row = r0 + wr * 32 + fm * 16 + kg * 4 + ii;
        float az  = acc[0][fm][fn][ii];
        float ar  = acc[1][fm][fn][ii];
        float axh = acc[2][fm][fn][ii];
        float arh = acc[3][fm][fn][ii];
        float pz, pr, xh_, rh_;
        if (L == 0) {
          const float* xr_ = xp1 + (size_t)row * 2112;
          pz  = xr_[j] + az + bhz;
          pr  = xr_[HH1 + j] + ar + bhr;
          xh_ = xr_[2 * HH1 + j];
          rh_ = arh + bhh;
        } else {
          pz  = az + biz + bhz;
          pr  = ar + bir + bhr;
          xh_ = axh + bih;
          rh_ = arh + bhh;
        }
        float zg = 1.f / (1.f + expf(-pz));
        float rg = 1.f / (1.f + expf(-pr));
        float hh = tanhf(xh_ + rg * rh_);
        float hp = hfP[(size_t)row * As1 + j];
        float hn = zg * hp + (1.f - zg) * hh;
        hfC[(size_t)row * As1 + j] = hn;
        hbC[(size_t)row * As1 + j] = f2b(hn);
      }
    }
  }
}

// ---------------- persistent group kernel: steps [s0,s1), h-ring depth R ----------------
__launch_bounds__(512, 2)
__global__ void k_pers(int s0, int s1, int R,
    const unsigned int* __restrict__ tab, unsigned int* __restrict__ cnt,
    const u16* __restrict__ WhT1, const u16* __restrict__ WiT2, const u16* __restrict__ WhT2,
    const u16* __restrict__ WiT3, const u16* __restrict__ WhT3, const u16* __restrict__ WoT,
    const float* __restrict__ xp1,
    const float* __restrict__ gbh1,
    const float* __restrict__ gbi2, const float* __restrict__ gbh2,
    const float* __restrict__ gbi3, const float* __restrict__ gbh3,
    const float* __restrict__ bo,
    u16* __restrict__ h1r, u16* __restrict__ h2r, u16* __restrict__ h3r,
    float* __restrict__ h1f, float* __restrict__ h2f, float* __restrict__ h3f,
    float* __restrict__ out)
{
  extern __shared__ __align__(16) char smem[];
  const int tid  = threadIdx.x;
  const int wgrp = tid >> 8;
  const int ltid = tid & 255;
  const int lane = tid & 63;
  const int wl   = (tid >> 6) & 3;
  const int wr = wl >> 1, wc = wl & 1;
  const int m16 = lane & 15, kg = lane >> 4;
  char* g0 = smem + wgrp * 65536;
  char* g1 = g0 + 32768;

  const unsigned e  = tab[blockIdx.x];
  const unsigned lo = e & 0xFFFFu, hi = e >> 16;
  const bool ksplit = (hi == 0xFFFFu);
  const unsigned item = (!ksplit && wgrp == 1) ? hi : lo;
  const int L  = (item >> 12) & 3;
  const int rr = (item >> 8) & 0xF;
  const int cc = item & 0xFF;
  const int r0 = rr * 64, j0 = cc * 64;

  // static config (ring bases, per-step slot offset added in loop)
  int H = 0, As0 = 0, Ws0 = 0, As1 = H3P, Ws1 = 0, n0 = 0, n1 = 0, k1off = 0;
  const u16 *A0base = nullptr, *W0p = nullptr, *A1base = nullptr, *W1p = nullptr;
  u16 *hbCbase = nullptr;
  float *hfbase = nullptr;
  const float *bi = nullptr, *bh = nullptr;
  bool do_epi = false;
  if (L == 0) {
    H = HH1;
    A1base = h1r; As1 = H1P; W1p = WhT1; Ws1 = H1P; n1 = 11;
    bh = gbh1; hbCbase = h1r; hfbase = h1f; do_epi = true;
  } else if (L == 1) {
    H = HH1; bi = gbi2; bh = gbh2; hbCbase = h2r; hfbase = h2f;
    As1 = H1P;
    if (wgrp == 0) { A0base = h1r; As0 = H1P; W0p = WiT2; Ws0 = H1P; n0 = 11; do_epi = true; }
    else           { A1base = h2r; W1p = WhT2; Ws1 = H1P; n1 = 11; }
  } else if (L == 2) {
    H = HH3; bi = gbi3; bh = gbh3; hbCbase = h3r; hfbase = h3f;
    As1 = H3P;
    if (wgrp == 0) {
      A0base = h2r; As0 = H1P; W0p = WiT3; Ws0 = H1P; n0 = 11;
      A1base = h3r; W1p = WhT3; Ws1 = H3P; n1 = 2; k1off = 0; do_epi = true;
    } else {
      A1base = h3r; W1p = WhT3; Ws1 = H3P; n1 = 13; k1off = 128;
    }
  }

  for (int s = s0; s < s1; ++s) {
    const int t = s - L;
    const int cur2 = s & 1, prv2 = cur2 ^ 1;
    const int curS = s % R, prvS = (s + R - 1) % R;

    if (t >= 0 && t < TT) {
      if (L == 3) {
        out_tile(h3r + (size_t)prvS * BB * H3P, WoT, bo, out, r0, t, g0, ltid, wr, wc, m16, kg);
      } else {
        const u16* A0 = A0base ? A0base + (size_t)prvS * BB * As0 : nullptr;
        const u16* A1 = A1base ? A1base + (size_t)prvS * BB * As1 : nullptr;

        f32x4 acc[4][2][2];
        { f32x4 z4 = {0.f,0.f,0.f,0.f};
          for (int g = 0; g < 4; ++g) for (int a = 0; a < 2; ++a) for (int b = 0; b < 2; ++b) acc[g][a][b] = z4; }

        gru_pipe(A0, As0, W0p, Ws0, A1, As1, W1p, Ws1, H, n0, n1, k1off,
                 r0, j0, g0, g1, wl, lane, wr, wc, m16, kg, acc);

        if (ksplit) {
          __syncthreads();
          float* red = (float*)smem;
          if (wgrp == 1) {
            float* b = red + ltid * 64;
            #pragma unroll
            for (int g = 0; g < 4; ++g)
              #pragma unroll
              for (int fm = 0; fm < 2; ++fm)
                #pragma unroll
                for (int fn = 0; fn < 2; ++fn)
                  *(f32x4*)(b + ((g * 2 + fm) * 2 + fn) * 4) = acc[g][fm][fn];
          }
          __syncthreads();
          if (wgrp == 0) {
            const float* b = red + ltid * 64;
            #pragma unroll
            for (int g = 0; g < 4; ++g)
              #pragma unroll
              for (int fm = 0; fm < 2; ++fm)
                #pragma unroll
                for (int fn = 0; fn < 2; ++fn)
                  acc[g][fm][fn] += *(const f32x4*)(b + ((g * 2 + fm) * 2 + fn) * 4);
          }
        }

        if (do_epi) {
          float* hfP = hfbase + (size_t)prv2 * BB * As1;
          float* hfC = hfbase + (size_t)cur2 * BB * As1;
          u16* hbC = hbCbase + (size_t)curS * BB * As1;
          #pragma unroll
          for (int fn = 0; fn < 2; ++fn) {
            int j = j0 + wc * 32 + fn * 16 + m16;
            if (j >= H) continue;
            float bhz = bh[j], bhr = bh[H + j], bhh = bh[2 * H + j];
            float biz = 0.f, bir = 0.f, bih = 0.f;
            if (L != 0) { biz = bi[j]; bir = bi[H + j]; bih = bi[2 * H + j]; }
            #pragma unroll
            for (int fm = 0; fm < 2; ++fm) {
              #pragma unroll
              for (int ii = 0; ii < 4; ++ii) {
                int row = r0 + wr * 32 + fm * 16 + kg * 4 + ii;
                float az  = acc[0][fm][fn][ii];
                float ar  = acc[1][fm][fn][ii];
                float axh = acc[2][fm][fn][ii];
                float arh = acc[3][fm][fn][ii];
                float pz, pr, xh_, rh_;
                if (L == 0) {
                  const float* xr_ = xp1 + (size_t)row * 2112;
                  pz  = xr_[j] + az + bhz;
                  pr  = xr_[HH1 + j] + ar + bhr;
                  xh_ = xr_[2 * HH1 + j];
                  rh_ = arh + bhh;
                } else {
                  pz  = az + biz + bhz;
                  pr  = ar + bir + bhr;
                  xh_ = axh + bih;
                  rh_ = arh + bhh;
                }
                float zg = 1.f / (1.f + expf(-pz));
                float rg = 1.f / (1.f + expf(-pr));
                float hh = tanhf(xh_ + rg * rh_);
                float hp = hfP[(size_t)row * As1 + j];
                float hn = zg * hp + (1.f - zg) * hh;
                hfC[(size_t)row * As1 + j] = hn;
                st_u16_sc(&hbC[(size_t)row * As1 + j], f2b(hn));
              }
            }
          }
        }
      }
    }

    // global step barrier (skip after last step of the group)
    if (s + 1 < s1) {
      asm volatile("s_waitcnt vmcnt(0)" ::: "memory");
      __syncthreads();
      if (tid == 0) {
        atomicAdd(&cnt[s], 1u);
        int guard = 0;
        while (__hip_atomic_load(&cnt[s], __ATOMIC_RELAXED, __HIP_MEMORY_SCOPE_AGENT) < 256u) {
          __builtin_amdgcn_s_sleep(2);
          if (++guard > (1 << 18)) break;   // fail loud, never hang
        }
      }
      __syncthreads();
    }
  }
}

// ---------------- host ----------------
extern "C" void kernel_launch(void* const* d_in, const int* in_sizes, int n_in,
                              void* d_out, int out_size, void* d_ws, size_t ws_size,
                              hipStream_t stream)
{
  const float* z    = (const float*)d_in[0];
  const float* W1   = (const float*)d_in[1];
  const float* b1   = (const float*)d_in[2];
  const float* gWi1 = (const float*)d_in[3];
  const float* gWh1 = (const float*)d_in[4];
  const float* gbi1 = (const float*)d_in[5];
  const float* gbh1 = (const float*)d_in[6];
  const float* gWi2 = (const float*)d_in[7];
  const float* gWh2 = (const float*)d_in[8];
  const float* gbi2 = (const float*)d_in[9];
  const float* gbh2 = (const float*)d_in[10];
  const float* gWi3 = (const float*)d_in[11];
  const float* gWh3 = (const float*)d_in[12];
  const float* gbi3 = (const float*)d_in[13];
  const float* gbh3 = (const float*)d_in[14];
  const float* Wo   = (const float*)d_in[15];
  const float* bo   = (const float*)d_in[16];

  char* ws = (char*)d_ws;
  float* x_f  = (float*)(ws + O_X);
  float* xp1  = (float*)(ws + O_XP1);
  float* h1f  = (float*)(ws + O_H1F);
  float* h2f  = (float*)(ws + O_H2F);
  float* h3f  = (float*)(ws + O_H3F);
  u16*   WhT1 = (u16*)(ws + O_WHT1);
  u16*   WiT2 = (u16*)(ws + O_WIT2);
  u16*   WhT2 = (u16*)(ws + O_WHT2);
  u16*   WiT3 = (u16*)(ws + O_WIT3);
  u16*   WhT3 = (u16*)(ws + O_WHT3);
  u16*   WoT  = (u16*)(ws + O_WOT);
  unsigned int* tab = (unsigned int*)(ws + O_TAB);
  unsigned int* cnt = (unsigned int*)(ws + O_CNT);

  hipFuncSetAttribute((const void*)k_pers,
                      hipFuncAttributeMaxDynamicSharedMemorySize, 131072);
  hipFuncSetAttribute((const void*)k_wave9,
                      hipFuncAttributeMaxDynamicSharedMemorySize, 131072);

  size_t avail = (ws_size > RING_BASE) ? (ws_size - RING_BASE) : 0;
  int R = (int)(avail / SLOTALL);
  if (R > NSTEP) R = NSTEP;

  k_maketab<<<1, 64, 0, stream>>>(tab);
  k_selu<<<(BB * LAT + 255) / 256, 256, 0, stream>>>(z, W1, b1, x_f);
  k_xp1<<<9 * 64, 256, 0, stream>>>(x_f, gWi1, gbi1, xp1);

  k_transpose<<<11 * 33, 256, 0, stream>>>(gWh1, WhT1, 701, 2103, 704, 2112);
  k_transpose<<<11 * 33, 256, 0, stream>>>(gWi2, WiT2, 701, 2103, 704, 2112);
  k_transpose<<<11 * 33, 256, 0, stream>>>(gWh2, WhT2, 701, 2103, 704, 2112);
  k_transpose<<<11 * 44, 256, 0, stream>>>(gWi3, WiT3, 701, 2703, 704, 2816);
  k_transpose<<<15 * 44, 256, 0, stream>>>(gWh3, WhT3, 901, 2703, 960, 2816);
  k_transpose<<<15 * 1, 256, 0, stream>>>(Wo, WoT, 901, 35, 960, 64);

  if (R >= 8) {
    u16* h1r = (u16*)(ws + RING_BASE);
    u16* h2r = (u16*)(ws + RING_BASE + (size_t)R * S1B);
    u16* h3r = (u16*)(ws + RING_BASE + (size_t)R * S1B * 2);
    hipMemsetAsync(ws + O_H1F, 0, ZERO_SMALL, stream);             // hf zeros
    hipMemsetAsync(ws + O_CNT, 0, NSTEP * 4, stream);
    hipMemsetAsync((char*)h1r + (size_t)(R - 1) * S1B, 0, S1B, stream); // read at s=0
    hipMemsetAsync((char*)h2r, 0, S1B, stream);                         // read at s=1
    hipMemsetAsync((char*)h3r + S3B, 0, S3B, stream);                   // read at s=2
    const int G = R - 1;
    for (int g0 = 0; g0 < NSTEP; g0 += G) {
      int g1 = g0 + G; if (g1 > NSTEP) g1 = NSTEP;
      k_pers<<<256, 512, 131072, stream>>>(g0, g1, R, tab, cnt,
          WhT1, WiT2, WhT2, WiT3, WhT3, WoT, xp1,
          gbh1, gbi2, gbh2, gbi3, gbh3, bo,
          h1r, h2r, h3r, h1f, h2f, h3f, (float*)d_out);
    }
  } else {
    u16* h1b = (u16*)(ws + O_H1B);
    u16* h2b = (u16*)(ws + O_H2B);
    u16* h3b = (u16*)(ws + O_H3B);
    hipMemsetAsync(ws + O_H1F, 0, ZERO_SMALL, stream);
    for (int s = 0; s < NSTEP; ++s)
      k_wave9<<<256, 512, 131072, stream>>>(s, tab,
          WhT1, WiT2, WhT2, WiT3, WhT3, WoT, xp1,
          gbh1, gbi2, gbh2, gbi3, gbh3, bo,
          h1f, h1b, h2f, h2b, h3f, h3b, (float*)d_out);
  }
}

// Round 14
// 7324.348 us; speedup vs baseline: 1.0123x; 1.0123x over previous
//
#include <hip/hip_runtime.h>
#include <hip/hip_bf16.h>
#include <math.h>

typedef unsigned short u16;
typedef __attribute__((ext_vector_type(4))) float f32x4;
typedef __attribute__((ext_vector_type(8))) short s16x8;

#define BB  512
#define TT  120
#define LAT 292
#define HH1 701
#define HH3 901
#define H1P 704
#define H3P 960
#define CH  35
#define NSTEP (TT + 3)
#define GRP 8

// ws layout (bytes)
static const size_t O_X    = 0;
static const size_t O_XP1  = 598016;                // 512*2112*4 f32
static const size_t O_H1F  = 4923392;               // f32 carry (1 slot used)
static const size_t O_H2F  = 7806976;
static const size_t O_H3F  = 10690560;
static const size_t O_H1B  = 14622720;              // 2-slot bf16 h (fallback)
static const size_t O_H2B  = 16064512;
static const size_t O_H3B  = 17506304;
static const size_t O_WHT1 = 19472384;
static const size_t O_WIT2 = 22446080;
static const size_t O_WHT2 = 25419776;
static const size_t O_WIT3 = 28393472;
static const size_t O_WHT3 = 32358400;
static const size_t O_WOT  = 37765120;
static const size_t O_TAB  = 37888000;              // 256*4
static const size_t O_CNT  = 37889024;              // NSTEP*4
static const size_t ZERO_SMALL = 14548992;          // O_H1F..O_H3B end
static const size_t RING_BASE  = 37900288;
static const size_t S1B = (size_t)BB * H1P * 2;     // 720896
static const size_t S3B = (size_t)BB * H3P * 2;     // 983040
static const size_t SLOTALL = S1B + S1B + S3B;      // 2424832

#define DSWZ(row, g) ((((g) ^ ((row) & 7)) << 4))

static __device__ __forceinline__ u16 f2b(float f){
  union { float f; unsigned int i; } v; v.f = f;
  unsigned int x = v.i;
  return (u16)((x + 0x7FFFu + ((x >> 16) & 1u)) >> 16);
}

#define GLL16(g, l) __builtin_amdgcn_global_load_lds( \
    (const __attribute__((address_space(1))) unsigned int*)(g), \
    (__attribute__((address_space(3))) unsigned int*)(l), 16, 0, 0)

static __device__ __forceinline__ void st_u16_sc(u16* p, u16 v) {
  asm volatile("global_store_short %0, %1, off sc0 sc1" :: "v"(p), "v"((unsigned)v) : "memory");
}

// ---------------- prologue kernels ----------------
__launch_bounds__(256)
__global__ void k_selu(const float* __restrict__ z, const float* __restrict__ W1,
                       const float* __restrict__ b1, float* __restrict__ x)
{
  int idx = blockIdx.x * 256 + threadIdx.x;
  if (idx >= BB * LAT) return;
  int b = idx / LAT, i = idx - b * LAT;
  float acc = b1[i];
  const float* zr = z + (size_t)b * LAT;
  for (int k = 0; k < LAT; ++k)
    acc += zr[k] * W1[k * LAT + i];
  const float alpha = 1.6732632423543772f, scale = 1.0507009873554805f;
  x[idx] = scale * (acc > 0.f ? acc : alpha * (expf(acc) - 1.f));
}

__launch_bounds__(256)
__global__ void k_xp1(const float* __restrict__ x, const float* __restrict__ Wi1,
                      const float* __restrict__ bi1, float* __restrict__ xp1)
{
  __shared__ float xs[8][LAT];
  int nb = blockIdx.x % 9, bb = blockIdx.x / 9;
  int n = nb * 256 + threadIdx.x;
  int b0 = bb * 8;
  for (int i = threadIdx.x; i < 8 * LAT; i += 256)
    xs[i / LAT][i % LAT] = x[(size_t)(b0 + i / LAT) * LAT + (i % LAT)];
  __syncthreads();
  if (n >= 2112) return;
  if (n >= 2103) { for (int r = 0; r < 8; ++r) xp1[(size_t)(b0 + r) * 2112 + n] = 0.f; return; }
  float bias = bi1[n];
  float acc[8];
  for (int r = 0; r < 8; ++r) acc[r] = bias;
  for (int k = 0; k < LAT; ++k) {
    float w = Wi1[(size_t)k * 2103 + n];
    #pragma unroll
    for (int r = 0; r < 8; ++r) acc[r] += xs[r][k] * w;
  }
  for (int r = 0; r < 8; ++r) xp1[(size_t)(b0 + r) * 2112 + n] = acc[r];
}

__launch_bounds__(256)
__global__ void k_transpose(const float* __restrict__ W, u16* __restrict__ WT,
                            int K, int N, int Kpad, int RowsPad)
{
  int tilesN = RowsPad / 64;
  int tk = blockIdx.x / tilesN, tn = blockIdx.x % tilesN;
  int k0 = tk * 64, n0 = tn * 64;
  __shared__ u16 lds[64][72];
  int tid = threadIdx.x;
  int nl = tid & 63, q = tid >> 6;
  for (int i = 0; i < 16; ++i) {
    int kl = q * 16 + i;
    int k = k0 + kl, n = n0 + nl;
    lds[kl][nl] = (k < K && n < N) ? f2b(W[(size_t)k * N + n]) : (u16)0;
  }
  __syncthreads();
  for (int i = 0; i < 16; ++i) {
    int rl = q * 16 + i;
    WT[(size_t)(n0 + rl) * Kpad + k0 + nl] = lds[nl][rl];
  }
}

__global__ void k_maketab(unsigned int* __restrict__ tab)
{
  if (threadIdx.x != 0 || blockIdx.x != 0) return;
  for (int x = 0; x < 8; ++x) {
    for (int li = 0; li < 32; ++li) {
      unsigned v;
      if (li < 15) {            // GRU3 ksplit
        int t3 = 15 * x + li;
        v = 0xFFFF0000u | (2u << 12) | ((unsigned)(t3 & 7) << 8) | (unsigned)(t3 >> 3);
      } else if (li < 26) {     // GRU2 ksplit
        int t2 = 11 * x + (li - 15);
        v = 0xFFFF0000u | (1u << 12) | ((unsigned)(t2 & 7) << 8) | (unsigned)(t2 >> 3);
      } else if (li < 31) {     // GRU1 pairs
        int pi = 5 * x + (li - 26);
        int i0 = 2 * pi, i1 = 2 * pi + 1;
        unsigned lo = ((unsigned)(i0 & 7) << 8) | (unsigned)(i0 >> 3);
        unsigned hw = ((unsigned)(i1 & 7) << 8) | (unsigned)(i1 >> 3);
        v = lo | (hw << 16);
      } else {
        if (x < 4) {            // OUT pairs
          unsigned lo = (3u << 12) | ((unsigned)(2 * x) << 8);
          unsigned hw = (3u << 12) | ((unsigned)(2 * x + 1) << 8);
          v = lo | (hw << 16);
        } else {                // leftover GRU1 pairs
          int pi = 40 + (x - 4);
          int i0 = 2 * pi, i1 = 2 * pi + 1;
          unsigned lo = ((unsigned)(i0 & 7) << 8) | (unsigned)(i0 >> 3);
          unsigned hw = ((unsigned)(i1 & 7) << 8) | (unsigned)(i1 >> 3);
          v = lo | (hw << 16);
        }
      }
      tab[x + 8 * li] = v;
    }
  }
}

// ---------------- K=64 staging + MFMA (r9-verbatim) ----------------
static __device__ __forceinline__ void stage_gru(
    const u16* __restrict__ A, int As, const u16* __restrict__ W, int Ws, int WH,
    int r0, int j0, int kbase, int wl, int lane, char* buf)
{
  #pragma unroll
  for (int i = 0; i < 8; ++i) {
    int slot = wl * 512 + i * 64 + lane;
    const u16* g;
    if (slot < 512) {
      int row = slot >> 3, gl = slot & 7;
      int gq = gl ^ (row & 7);
      g = A + (size_t)(r0 + row) * As + kbase + gq * 8;
    } else {
      int s2 = slot - 512;
      int gate = s2 >> 9, loc = s2 & 511;
      int col = loc >> 3, gl = loc & 7;
      int gq = gl ^ (col & 7);
      g = W + ((size_t)gate * WH + j0 + col) * Ws + kbase + gq * 8;
    }
    char* l = buf + (wl * 512 + i * 64) * 16;
    GLL16(g, l);
  }
}

template<int HACC>
static __device__ __forceinline__ void mm_gru(const char* gb, int wr, int wc, int m16, int kg,
                                              f32x4 (&acc)[4][2][2])
{
  #pragma unroll
  for (int s = 0; s < 2; ++s) {
    s16x8 af[2];
    #pragma unroll
    for (int fm = 0; fm < 2; ++fm) {
      int row = wr * 32 + fm * 16 + m16;
      af[fm] = *(const s16x8*)(gb + row * 128 + DSWZ(row, s * 4 + kg));
    }
    #pragma unroll
    for (int g = 0; g < 3; ++g) {
      #pragma unroll
      for (int fn = 0; fn < 2; ++fn) {
        int col = wc * 32 + fn * 16 + m16;
        s16x8 bf = *(const s16x8*)(gb + 8192 + g * 8192 + col * 128 + DSWZ(col, s * 4 + kg));
        const int ai = (g == 2) ? HACC : g;
        #pragma unroll
        for (int fm = 0; fm < 2; ++fm)
          acc[ai][fm][fn] = __builtin_amdgcn_mfma_f32_16x16x32_bf16(af[fm], bf, acc[ai][fm][fn], 0, 0, 0);
      }
    }
  }
}

static __device__ __forceinline__ void gru_pipe(
    const u16* A0, int As0, const u16* W0, int Ws0,
    const u16* A1, int As1, const u16* W1p, int Ws1,
    int WH, int n0, int n1, int k1off,
    int r0, int j0, char* g0, char* g1, int wl, int lane,
    int wr, int wc, int m16, int kg, f32x4 (&acc)[4][2][2])
{
  const int n = n0 + n1;
#define STG(C, BUF) do { int c_ = (C); \
    if (c_ < n0) stage_gru(A0, As0, W0, Ws0, WH, r0, j0, c_ * 64, wl, lane, (BUF)); \
    else         stage_gru(A1, As1, W1p, Ws1, WH, r0, j0, (c_ - n0) * 64 + k1off, wl, lane, (BUF)); \
  } while (0)
  STG(0, g0);
  __syncthreads();
  for (int ch = 0; ch < n; ch += 2) {
    if (ch + 1 < n) STG(ch + 1, g1);
    if (ch < n0) mm_gru<2>(g0, wr, wc, m16, kg, acc);
    else         mm_gru<3>(g0, wr, wc, m16, kg, acc);
    __syncthreads();
    if (ch + 1 >= n) break;
    if (ch + 2 < n) STG(ch + 2, g0);
    if (ch + 1 < n0) mm_gru<2>(g1, wr, wc, m16, kg, acc);
    else             mm_gru<3>(g1, wr, wc, m16, kg, acc);
    __syncthreads();
  }
#undef STG
}

// ---------------- OUT tile (r9-verbatim core) ----------------
static __device__ __forceinline__ void out_tile(
    const u16* __restrict__ Ab, const u16* __restrict__ WoT, const float* __restrict__ bo,
    float* __restrict__ out, int r0, int t,
    char* g0, int ltid, int wr, int wc, int m16, int kg)
{
  f32x4 acc2[2][2];
  { f32x4 z4 = {0.f,0.f,0.f,0.f}; for (int a=0;a<2;++a) for (int b=0;b<2;++b) acc2[a][b]=z4; }
  int4 ra[2], rb2[2];
  const int n = H3P / 64;                 // 15
  #pragma unroll
  for (int it = 0; it < 2; ++it) {
    int gi = it * 256 + ltid; int r = gi >> 3, gq = gi & 7;
    ra[it]  = *(const int4*)(Ab + (size_t)(r0 + r) * H3P + gq * 8);
    rb2[it] = *(const int4*)(WoT + (size_t)r * H3P + gq * 8);
  }
  #pragma unroll
  for (int it = 0; it < 2; ++it) {
    int gi = it * 256 + ltid; int r = gi >> 3, gq = gi & 7;
    *(int4*)(g0 + r * 128 + DSWZ(r, gq)) = ra[it];
    *(int4*)(g0 + 8192 + r * 128 + DSWZ(r, gq)) = rb2[it];
  }
  __syncthreads();
  for (int ch = 0; ch < n; ++ch) {
    const bool have = (ch + 1 < n);
    if (have) {
      int kb = (ch + 1) * 64;
      #pragma unroll
      for (int it = 0; it < 2; ++it) {
        int gi = it * 256 + ltid; int r = gi >> 3, gq = gi & 7;
        ra[it]  = *(const int4*)(Ab + (size_t)(r0 + r) * H3P + kb + gq * 8);
        rb2[it] = *(const int4*)(WoT + (size_t)r * H3P + kb + gq * 8);
      }
    }
    #pragma unroll
    for (int s2 = 0; s2 < 2; ++s2) {
      s16x8 af[2], bf[2];
      #pragma unroll
      for (int fm = 0; fm < 2; ++fm) {
        int row = wr * 32 + fm * 16 + m16;
        af[fm] = *(const s16x8*)(g0 + row * 128 + DSWZ(row, s2 * 4 + kg));
      }
      #pragma unroll
      for (int fn = 0; fn < 2; ++fn) {
        int col = wc * 32 + fn * 16 + m16;
        bf[fn] = *(const s16x8*)(g0 + 8192 + col * 128 + DSWZ(col, s2 * 4 + kg));
      }
      #pragma unroll
      for (int fm = 0; fm < 2; ++fm)
        #pragma unroll
        for (int fn = 0; fn < 2; ++fn)
          acc2[fm][fn] = __builtin_amdgcn_mfma_f32_16x16x32_bf16(af[fm], bf[fn], acc2[fm][fn], 0, 0, 0);
    }
    if (have) {
      __syncthreads();
      #pragma unroll
      for (int it = 0; it < 2; ++it) {
        int gi = it * 256 + ltid; int r = gi >> 3, gq = gi & 7;
        *(int4*)(g0 + r * 128 + DSWZ(r, gq)) = ra[it];
        *(int4*)(g0 + 8192 + r * 128 + DSWZ(r, gq)) = rb2[it];
      }
      __syncthreads();
    }
  }
  __syncthreads();
  float (*ldsL)[68] = (float (*)[68])g0;
  #pragma unroll
  for (int fn = 0; fn < 2; ++fn) {
    int col = wc * 32 + fn * 16 + m16;
    float bov = (col < CH) ? bo[col] : 0.f;
    #pragma unroll
    for (int fm = 0; fm < 2; ++fm)
      #pragma unroll
      for (int ii = 0; ii < 4; ++ii)
        ldsL[wr * 32 + fm * 16 + kg * 4 + ii][col] = acc2[fm][fn][ii] + bov;
  }
  __syncthreads();
  if (ltid < 64) {
    int b = r0 + ltid;
    float mx = -1e30f;
    for (int c2 = 0; c2 < CH; ++c2) mx = fmaxf(mx, ldsL[ltid][c2]);
    float sum = 0.f;
    for (int c2 = 0; c2 < CH; ++c2) sum += expf(ldsL[ltid][c2] - mx);
    float inv = 1.f / sum;
    size_t ob = ((size_t)b * TT + t) * CH;
    for (int c2 = 0; c2 < CH; ++c2) out[ob + c2] = expf(ldsL[ltid][c2] - mx) * inv;
  }
}

// ---------------- fallback kernel: exact r9 per-step launch ----------------
__launch_bounds__(512, 2)
__global__ void k_wave9(int s, const unsigned int* __restrict__ tab,
    const u16* __restrict__ WhT1, const u16* __restrict__ WiT2, const u16* __restrict__ WhT2,
    const u16* __restrict__ WiT3, const u16* __restrict__ WhT3, const u16* __restrict__ WoT,
    const float* __restrict__ xp1,
    const float* __restrict__ gbh1,
    const float* __restrict__ gbi2, const float* __restrict__ gbh2,
    const float* __restrict__ gbi3, const float* __restrict__ gbh3,
    const float* __restrict__ bo,
    float* __restrict__ h1f, u16* __restrict__ h1b,
    float* __restrict__ h2f, u16* __restrict__ h2b,
    float* __restrict__ h3f, u16* __restrict__ h3b,
    float* __restrict__ out)
{
  extern __shared__ __align__(16) char smem[];
  const int tid  = threadIdx.x;
  const int wgrp = tid >> 8;
  const int ltid = tid & 255;
  const int lane = tid & 63;
  const int wl   = (tid >> 6) & 3;
  const int wr = wl >> 1, wc = wl & 1;
  const int m16 = lane & 15, kg = lane >> 4;
  char* g0 = smem + wgrp * 65536;
  char* g1 = g0 + 32768;

  const unsigned e  = tab[blockIdx.x];
  const unsigned lo = e & 0xFFFFu, hi = e >> 16;
  const bool ksplit = (hi == 0xFFFFu);
  const unsigned item = (!ksplit && wgrp == 1) ? hi : lo;
  const int L  = (item >> 12) & 3;
  const int rr = (item >> 8) & 0xF;
  const int cc = item & 0xFF;
  const int t = s - L;
  if (t < 0 || t >= TT) return;
  const int cur = s & 1, prv = cur ^ 1;

  if (L == 3) {
    out_tile(h3b + (size_t)prv * BB * H3P, WoT, bo, out, rr * 64, t, g0, ltid, wr, wc, m16, kg);
    return;
  }

  int H;
  const u16 *A0 = nullptr, *W0 = nullptr, *A1 = nullptr, *W1p = nullptr;
  int As0 = 0, Ws0 = 0, As1 = 0, Ws1 = 0, n0 = 0, n1 = 0, k1off = 0;
  const float *bi = nullptr, *bh;
  float *hfP, *hfC; u16 *hbC;
  if (L == 0) {
    H = HH1;
    A1 = h1b + (size_t)prv * BB * H1P; As1 = H1P; W1p = WhT1; Ws1 = H1P; n1 = 11;
    bh = gbh1;
    hfP = h1f + (size_t)prv * BB * H1P; hfC = h1f + (size_t)cur * BB * H1P;
    hbC = h1b + (size_t)cur * BB * H1P;
  } else if (L == 1) {
    H = HH1; bi = gbi2; bh = gbh2;
    hfP = h2f + (size_t)prv * BB * H1P; hfC = h2f + (size_t)cur * BB * H1P;
    hbC = h2b + (size_t)cur * BB * H1P;
    if (wgrp == 0) { A0 = h1b + (size_t)prv * BB * H1P; As0 = H1P; W0 = WiT2; Ws0 = H1P; n0 = 11; As1 = H1P; }
    else           { A1 = h2b + (size_t)prv * BB * H1P; As1 = H1P; W1p = WhT2; Ws1 = H1P; n1 = 11; }
  } else {
    H = HH3; bi = gbi3; bh = gbh3;
    hfP = h3f + (size_t)prv * BB * H3P; hfC = h3f + (size_t)cur * BB * H3P;
    hbC = h3b + (size_t)cur * BB * H3P;
    if (wgrp == 0) {
      A0 = h2b + (size_t)prv * BB * H1P; As0 = H1P; W0 = WiT3; Ws0 = H1P; n0 = 11;
      A1 = h3b + (size_t)prv * BB * H3P; As1 = H3P; W1p = WhT3; Ws1 = H3P; n1 = 2; k1off = 0;
    } else {
      A1 = h3b + (size_t)prv * BB * H3P; As1 = H3P; W1p = WhT3; Ws1 = H3P; n1 = 13; k1off = 128;
    }
  }
  const int r0 = rr * 64, j0 = cc * 64;

  f32x4 acc[4][2][2];
  { f32x4 z4 = {0.f, 0.f, 0.f, 0.f};
    for (int g = 0; g < 4; ++g) for (int a = 0; a < 2; ++a) for (int b = 0; b < 2; ++b) acc[g][a][b] = z4; }

  gru_pipe(A0, As0, W0, Ws0, A1, As1, W1p, Ws1, H, n0, n1, k1off,
           r0, j0, g0, g1, wl, lane, wr, wc, m16, kg, acc);

  if (ksplit) {
    __syncthreads();
    float* red = (float*)smem;
    if (wgrp == 1) {
      float* b = red + ltid * 64;
      #pragma unroll
      for (int g = 0; g < 4; ++g)
        #pragma unroll
        for (int fm = 0; fm < 2; ++fm)
          #pragma unroll
          for (int fn = 0; fn < 2; ++fn)
            *(f32x4*)(b + ((g * 2 + fm) * 2 + fn) * 4) = acc[g][fm][fn];
    }
    __syncthreads();
    if (wgrp == 1) return;
    {
      const float* b = red + ltid * 64;
      #pragma unroll
      for (int g = 0; g < 4; ++g)
        #pragma unroll
        for (int fm = 0; fm < 2; ++fm)
          #pragma unroll
          for (int fn = 0; fn < 2; ++fn)
            acc[g][fm][fn] += *(const f32x4*)(b + ((g * 2 + fm) * 2 + fn) * 4);
    }
  }

  #pragma unroll
  for (int fn = 0; fn < 2; ++fn) {
    int j = j0 + wc * 32 + fn * 16 + m16;
    if (j >= H) continue;
    float bhz = bh[j], bhr = bh[H + j], bhh = bh[2 * H + j];
    float biz = 0.f, bir = 0.f, bih = 0.f;
    if (L != 0) { biz = bi[j]; bir = bi[H + j]; bih = bi[2 * H + j]; }
    #pragma unroll
    for (int fm = 0; fm < 2; ++fm) {
      #pragma unroll
      for (int ii = 0; ii < 4; ++ii) {
        int row = r0 + wr * 32 + fm * 16 + kg * 4 + ii;
        float az  = acc[0][fm][fn][ii];
        float ar  = acc[1][fm][fn][ii];
        float axh = acc[2][fm][fn][ii];
        float arh = acc[3][fm][fn][ii];
        float pz, pr, xh_, rh_;
        if (L == 0) {
          const float* xr_ = xp1 + (size_t)row * 2112;
          pz  = xr_[j] + az + bhz;
          pr  = xr_[HH1 + j] + ar + bhr;
          xh_ = xr_[2 * HH1 + j];
          rh_ = arh + bhh;
        } else {
          pz  = az + biz + bhz;
          pr  = ar + bir + bhr;
          xh_ = axh + bih;
          rh_ = arh + bhh;
        }
        float zg = 1.f / (1.f + expf(-pz));
        float rg = 1.f / (1.f + expf(-pr));
        float hh = tanhf(xh_ + rg * rh_);
        float hp = hfP[(size_t)row * As1 + j];
        float hn = zg * hp + (1.f - zg) * hh;
        hfC[(size_t)row * As1 + j] = hn;
        hbC[(size_t)row * As1 + j] = f2b(hn);
      }
    }
  }
}

// ---------------- grouped persistent kernel: steps [s0,s1), ring depth R=GRP ----------------
// hp carry in registers; loaded from hf at group start, stored at group end.
__launch_bounds__(512, 2)
__global__ void k_pers(int s0, int s1, int R,
    const unsigned int* __restrict__ tab, unsigned int* __restrict__ cnt,
    const u16* __restrict__ WhT1, const u16* __restrict__ WiT2, const u16* __restrict__ WhT2,
    const u16* __restrict__ WiT3, const u16* __restrict__ WhT3, const u16* __restrict__ WoT,
    const float* __restrict__ xp1,
    const float* __restrict__ gbh1,
    const float* __restrict__ gbi2, const float* __restrict__ gbh2,
    const float* __restrict__ gbi3, const float* __restrict__ gbh3,
    const float* __restrict__ bo,
    u16* __restrict__ h1r, u16* __restrict__ h2r, u16* __restrict__ h3r,
    float* __restrict__ h1f, float* __restrict__ h2f, float* __restrict__ h3f,
    float* __restrict__ out)
{
  extern __shared__ __align__(16) char smem[];
  const int tid  = threadIdx.x;
  const int wgrp = tid >> 8;
  const int ltid = tid & 255;
  const int lane = tid & 63;
  const int wl   = (tid >> 6) & 3;
  const int wr = wl >> 1, wc = wl & 1;
  const int m16 = lane & 15, kg = lane >> 4;
  char* g0 = smem + wgrp * 65536;
  char* g1 = g0 + 32768;

  const unsigned e  = tab[blockIdx.x];
  const unsigned lo = e & 0xFFFFu, hi = e >> 16;
  const bool ksplit = (hi == 0xFFFFu);
  const unsigned item = (!ksplit && wgrp == 1) ? hi : lo;
  const int L  = (item >> 12) & 3;
  const int rr = (item >> 8) & 0xF;
  const int cc = item & 0xFF;
  const int r0 = rr * 64, j0 = cc * 64;

  int H = 0, As0 = 0, Ws0 = 0, As1 = H3P, Ws1 = 0, n0 = 0, n1 = 0, k1off = 0;
  const u16 *A0base = nullptr, *W0p = nullptr, *A1base = nullptr, *W1p = nullptr;
  u16 *hbCbase = nullptr;
  float *hfbase = nullptr;
  const float *bi = nullptr, *bh = nullptr;
  bool do_epi = false;
  if (L == 0) {
    H = HH1;
    A1base = h1r; As1 = H1P; W1p = WhT1; Ws1 = H1P; n1 = 11;
    bh = gbh1; hbCbase = h1r; hfbase = h1f; do_epi = true;
  } else if (L == 1) {
    H = HH1; bi = gbi2; bh = gbh2; hbCbase = h2r; hfbase = h2f;
    As1 = H1P;
    if (wgrp == 0) { A0base = h1r; As0 = H1P; W0p = WiT2; Ws0 = H1P; n0 = 11; do_epi = true; }
    else           { A1base = h2r; W1p = WhT2; Ws1 = H1P; n1 = 11; }
  } else if (L == 2) {
    H = HH3; bi = gbi3; bh = gbh3; hbCbase = h3r; hfbase = h3f;
    As1 = H3P;
    if (wgrp == 0) {
      A0base = h2r; As0 = H1P; W0p = WiT3; Ws0 = H1P; n0 = 11;
      A1base = h3r; W1p = WhT3; Ws1 = H3P; n1 = 2; k1off = 0; do_epi = true;
    } else {
      A1base = h3r; W1p = WhT3; Ws1 = H3P; n1 = 13; k1off = 128;
    }
  }

  // ---- load hp from hf (group start) ----
  f32x4 hp_[2][2];
  { f32x4 z4 = {0.f,0.f,0.f,0.f}; for (int a=0;a<2;++a) for (int b=0;b<2;++b) hp_[a][b]=z4; }
  if (do_epi) {
    #pragma unroll
    for (int fn = 0; fn < 2; ++fn) {
      int j = j0 + wc * 32 + fn * 16 + m16;
      if (j >= H) continue;
      #pragma unroll
      for (int fm = 0; fm < 2; ++fm)
        #pragma unroll
        for (int ii = 0; ii < 4; ++ii) {
          int row = r0 + wr * 32 + fm * 16 + kg * 4 + ii;
          hp_[fn][fm][ii] = hfbase[(size_t)row * As1 + j];
        }
    }
  }

  for (int s = s0; s < s1; ++s) {
    const int t = s - L;
    const int curS = s % R, prvS = (s + R - 1) % R;

    if (t >= 0 && t < TT) {
      if (L == 3) {
        out_tile(h3r + (size_t)prvS * BB * H3P, WoT, bo, out, r0, t, g0, ltid, wr, wc, m16, kg);
      } else {
        const u16* A0 = A0base ? A0base + (size_t)prvS * BB * As0 : nullptr;
        const u16* A1 = A1base ? A1base + (size_t)prvS * BB * As1 : nullptr;

        f32x4 acc[4][2][2];
        { f32x4 z4 = {0.f,0.f,0.f,0.f};
          for (int g = 0; g < 4; ++g) for (int a = 0; a < 2; ++a) for (int b = 0; b < 2; ++b) acc[g][a][b] = z4; }

        gru_pipe(A0, As0, W0p, Ws0, A1, As1, W1p, Ws1, H, n0, n1, k1off,
                 r0, j0, g0, g1, wl, lane, wr, wc, m16, kg, acc);

        if (ksplit) {
          __syncthreads();
          float* red = (float*)smem;
          if (wgrp == 1) {
            float* b = red + ltid * 64;
            #pragma unroll
            for (int g = 0; g < 4; ++g)
              #pragma unroll
              for (int fm = 0; fm < 2; ++fm)
                #pragma unroll
                for (int fn = 0; fn < 2; ++fn)
                  *(f32x4*)(b + ((g * 2 + fm) * 2 + fn) * 4) = acc[g][fm][fn];
          }
          __syncthreads();
          if (wgrp == 0) {
            const float* b = red + ltid * 64;
            #pragma unroll
            for (int g = 0; g < 4; ++g)
              #pragma unroll
              for (int fm = 0; fm < 2; ++fm)
                #pragma unroll
                for (int fn = 0; fn < 2; ++fn)
                  acc[g][fm][fn] += *(const f32x4*)(b + ((g * 2 + fm) * 2 + fn) * 4);
          }
        }

        if (do_epi) {
          u16* hbC = hbCbase + (size_t)curS * BB * As1;
          #pragma unroll
          for (int fn = 0; fn < 2; ++fn) {
            int j = j0 + wc * 32 + fn * 16 + m16;
            if (j >= H) continue;
            float bhz = bh[j], bhr = bh[H + j], bhh = bh[2 * H + j];
            float biz = 0.f, bir = 0.f, bih = 0.f;
            if (L != 0) { biz = bi[j]; bir = bi[H + j]; bih = bi[2 * H + j]; }
            #pragma unroll
            for (int fm = 0; fm < 2; ++fm) {
              #pragma unroll
              for (int ii = 0; ii < 4; ++ii) {
                int row = r0 + wr * 32 + fm * 16 + kg * 4 + ii;
                float az  = acc[0][fm][fn][ii];
                float ar  = acc[1][fm][fn][ii];
                float axh = acc[2][fm][fn][ii];
                float arh = acc[3][fm][fn][ii];
                float pz, pr, xh_, rh_;
                if (L == 0) {
                  const float* xr_ = xp1 + (size_t)row * 2112;
                  pz  = xr_[j] + az + bhz;
                  pr  = xr_[HH1 + j] + ar + bhr;
                  xh_ = xr_[2 * HH1 + j];
                  rh_ = arh + bhh;
                } else {
                  pz  = az + biz + bhz;
                  pr  = ar + bir + bhr;
                  xh_ = axh + bih;
                  rh_ = arh + bhh;
                }
                float zg = 1.f / (1.f + expf(-pz));
                float rg = 1.f / (1.f + expf(-pr));
                float hh = tanhf(xh_ + rg * rh_);
                float hn = zg * hp_[fn][fm][ii] + (1.f - zg) * hh;
                hp_[fn][fm][ii] = hn;
                st_u16_sc(&hbC[(size_t)row * As1 + j], f2b(hn));
              }
            }
          }
        }
      }
    }

    // global step barrier within group (skip after last step)
    if (s + 1 < s1) {
      asm volatile("s_waitcnt vmcnt(0)" ::: "memory");
      __syncthreads();
      if (tid == 0) {
        atomicAdd(&cnt[s], 1u);
        int guard = 0;
        while (__hip_atomic_load(&cnt[s], __ATOMIC_RELAXED, __HIP_MEMORY_SCOPE_AGENT) < 256u) {
          __builtin_amdgcn_s_sleep(2);
          if (++guard > (1 << 18)) break;   // fail loud, never hang
        }
      }
      __syncthreads();
    }
  }

  // ---- store hp to hf (group end) ----
  if (do_epi) {
    #pragma unroll
    for (int fn = 0; fn < 2; ++fn) {
      int j = j0 + wc * 32 + fn * 16 + m16;
      if (j >= H) continue;
      #pragma unroll
      for (int fm = 0; fm < 2; ++fm)
        #pragma unroll
        for (int ii = 0; ii < 4; ++ii) {
          int row = r0 + wr * 32 + fm * 16 + kg * 4 + ii;
          hfbase[(size_t)row * As1 + j] = hp_[fn][fm][ii];
        }
    }
  }
}

// ---------------- host ----------------
extern "C" void kernel_launch(void* const* d_in, const int* in_sizes, int n_in,
                              void* d_out, int out_size, void* d_ws, size_t ws_size,
                              hipStream_t stream)
{
  const float* z    = (const float*)d_in[0];
  const float* W1   = (const float*)d_in[1];
  const float* b1   = (const float*)d_in[2];
  const float* gWi1 = (const float*)d_in[3];
  const float* gWh1 = (const float*)d_in[4];
  const float* gbi1 = (const float*)d_in[5];
  const float* gbh1 = (const float*)d_in[6];
  const float* gWi2 = (const float*)d_in[7];
  const float* gWh2 = (const float*)d_in[8];
  const float* gbi2 = (const float*)d_in[9];
  const float* gbh2 = (const float*)d_in[10];
  const float* gWi3 = (const float*)d_in[11];
  const float* gWh3 = (const float*)d_in[12];
  const float* gbi3 = (const float*)d_in[13];
  const float* gbh3 = (const float*)d_in[14];
  const float* Wo   = (const float*)d_in[15];
  const float* bo   = (const float*)d_in[16];

  char* ws = (char*)d_ws;
  float* x_f  = (float*)(ws + O_X);
  float* xp1  = (float*)(ws + O_XP1);
  float* h1f  = (float*)(ws + O_H1F);
  float* h2f  = (float*)(ws + O_H2F);
  float* h3f  = (float*)(ws + O_H3F);
  u16*   WhT1 = (u16*)(ws + O_WHT1);
  u16*   WiT2 = (u16*)(ws + O_WIT2);
  u16*   WhT2 = (u16*)(ws + O_WHT2);
  u16*   WiT3 = (u16*)(ws + O_WIT3);
  u16*   WhT3 = (u16*)(ws + O_WHT3);
  u16*   WoT  = (u16*)(ws + O_WOT);
  unsigned int* tab = (unsigned int*)(ws + O_TAB);
  unsigned int* cnt = (unsigned int*)(ws + O_CNT);

  hipFuncSetAttribute((const void*)k_pers,
                      hipFuncAttributeMaxDynamicSharedMemorySize, 131072);
  hipFuncSetAttribute((const void*)k_wave9,
                      hipFuncAttributeMaxDynamicSharedMemorySize, 131072);

  size_t avail = (ws_size > RING_BASE) ? (ws_size - RING_BASE) : 0;
  const bool big = (avail >= (size_t)GRP * SLOTALL);

  k_maketab<<<1, 64, 0, stream>>>(tab);
  k_selu<<<(BB * LAT + 255) / 256, 256, 0, stream>>>(z, W1, b1, x_f);
  k_xp1<<<9 * 64, 256, 0, stream>>>(x_f, gWi1, gbi1, xp1);

  k_transpose<<<11 * 33, 256, 0, stream>>>(gWh1, WhT1, 701, 2103, 704, 2112);
  k_transpose<<<11 * 33, 256, 0, stream>>>(gWi2, WiT2, 701, 2103, 704, 2112);
  k_transpose<<<11 * 33, 256, 0, stream>>>(gWh2, WhT2, 701, 2103, 704, 2112);
  k_transpose<<<11 * 44, 256, 0, stream>>>(gWi3, WiT3, 701, 2703, 704, 2816);
  k_transpose<<<15 * 44, 256, 0, stream>>>(gWh3, WhT3, 901, 2703, 960, 2816);
  k_transpose<<<15 * 1, 256, 0, stream>>>(Wo, WoT, 901, 35, 960, 64);

  if (big) {
    u16* h1r = (u16*)(ws + RING_BASE);
    u16* h2r = (u16*)(ws + RING_BASE + (size_t)GRP * S1B);
    u16* h3r = (u16*)(ws + RING_BASE + (size_t)GRP * S1B * 2);
    hipMemsetAsync(ws + O_H1F, 0, ZERO_SMALL, stream);                       // hf zeros
    hipMemsetAsync(ws + O_CNT, 0, NSTEP * 4, stream);
    hipMemsetAsync((char*)h1r + (size_t)(GRP - 1) * S1B, 0, S1B, stream);    // read at s=0
    hipMemsetAsync((char*)h2r, 0, S1B, stream);                              // read at s=1
    hipMemsetAsync((char*)h3r + S3B, 0, S3B, stream);                        // read at s=2
    for (int g0 = 0; g0 < NSTEP; g0 += GRP) {
      int g1 = g0 + GRP; if (g1 > NSTEP) g1 = NSTEP;
      k_pers<<<256, 512, 131072, stream>>>(g0, g1, GRP, tab, cnt,
          WhT1, WiT2, WhT2, WiT3, WhT3, WoT, xp1,
          gbh1, gbi2, gbh2, gbi3, gbh3, bo,
          h1r, h2r, h3r, h1f, h2f, h3f, (float*)d_out);
    }
  } else {
    u16* h1b = (u16*)(ws + O_H1B);
    u16* h2b = (u16*)(ws + O_H2B);
    u16* h3b = (u16*)(ws + O_H3B);
    hipMemsetAsync(ws + O_H1F, 0, ZERO_SMALL, stream);
    for (int s = 0; s < NSTEP; ++s)
      k_wave9<<<256, 512, 131072, stream>>>(s, tab,
          WhT1, WiT2, WhT2, WiT3, WhT3, WoT, xp1,
          gbh1, gbi2, gbh2, gbi3, gbh3, bo,
          h1f, h1b, h2f, h2b, h3f, h3b, (float*)d_out);
  }
}

// Round 16
// 6494.545 us; speedup vs baseline: 1.1416x; 1.1278x over previous
//
#include <hip/hip_runtime.h>
#include <hip/hip_bf16.h>
#include <math.h>

typedef unsigned short u16;
typedef __attribute__((ext_vector_type(4))) float f32x4;
typedef __attribute__((ext_vector_type(8))) short s16x8;
typedef __attribute__((ext_vector_type(4))) int i32x4;

#define BB  512
#define TT  120
#define LAT 292
#define HH1 701
#define HH3 901
#define H1P 704
#define H3P 960
#define CH  35
#define NSTEP (TT + 3)
#define GRP 8

// ws layout (bytes)
static const size_t O_X    = 0;
static const size_t O_XP1  = 598016;                // 512*2112*4 f32
static const size_t O_H1F  = 4923392;               // f32 carry
static const size_t O_H2F  = 7806976;
static const size_t O_H3F  = 10690560;
static const size_t O_H1B  = 14622720;              // 2-slot bf16 h (fallback)
static const size_t O_H2B  = 16064512;
static const size_t O_H3B  = 17506304;
static const size_t O_WHT1 = 19472384;
static const size_t O_WIT2 = 22446080;
static const size_t O_WHT2 = 25419776;
static const size_t O_WIT3 = 28393472;
static const size_t O_WHT3 = 32358400;
static const size_t O_WOT  = 37765120;
static const size_t O_TAB  = 37888000;              // 256*4
static const size_t O_CNT  = 37889024;              // NSTEP*4
static const size_t ZERO_SMALL = 14548992;          // O_H1F..O_H3B end
static const size_t RING_BASE  = 37900288;
static const size_t S1B = (size_t)BB * H1P * 2;     // 720896
static const size_t S3B = (size_t)BB * H3P * 2;     // 983040
static const size_t SLOTALL = S1B + S1B + S3B;      // 2424832

#define DSWZ(row, g) ((((g) ^ ((row) & 7)) << 4))

static __device__ __forceinline__ u16 f2b(float f){
  union { float f; unsigned int i; } v; v.f = f;
  unsigned int x = v.i;
  return (u16)((x + 0x7FFFu + ((x >> 16) & 1u)) >> 16);
}

#define GLL16(g, l) __builtin_amdgcn_global_load_lds( \
    (const __attribute__((address_space(1))) unsigned int*)(g), \
    (__attribute__((address_space(3))) unsigned int*)(l), 16, 0, 0)

static __device__ __forceinline__ void st_16_sc(void* p, i32x4 v) {
  asm volatile("global_store_dwordx4 %0, %1, off sc0 sc1" :: "v"(p), "v"(v) : "memory");
}

// ---------------- prologue kernels ----------------
__launch_bounds__(256)
__global__ void k_selu(const float* __restrict__ z, const float* __restrict__ W1,
                       const float* __restrict__ b1, float* __restrict__ x)
{
  int idx = blockIdx.x * 256 + threadIdx.x;
  if (idx >= BB * LAT) return;
  int b = idx / LAT, i = idx - b * LAT;
  float acc = b1[i];
  const float* zr = z + (size_t)b * LAT;
  for (int k = 0; k < LAT; ++k)
    acc += zr[k] * W1[k * LAT + i];
  const float alpha = 1.6732632423543772f, scale = 1.0507009873554805f;
  x[idx] = scale * (acc > 0.f ? acc : alpha * (expf(acc) - 1.f));
}

__launch_bounds__(256)
__global__ void k_xp1(const float* __restrict__ x, const float* __restrict__ Wi1,
                      const float* __restrict__ bi1, float* __restrict__ xp1)
{
  __shared__ float xs[8][LAT];
  int nb = blockIdx.x % 9, bb = blockIdx.x / 9;
  int n = nb * 256 + threadIdx.x;
  int b0 = bb * 8;
  for (int i = threadIdx.x; i < 8 * LAT; i += 256)
    xs[i / LAT][i % LAT] = x[(size_t)(b0 + i / LAT) * LAT + (i % LAT)];
  __syncthreads();
  if (n >= 2112) return;
  if (n >= 2103) { for (int r = 0; r < 8; ++r) xp1[(size_t)(b0 + r) * 2112 + n] = 0.f; return; }
  float bias = bi1[n];
  float acc[8];
  for (int r = 0; r < 8; ++r) acc[r] = bias;
  for (int k = 0; k < LAT; ++k) {
    float w = Wi1[(size_t)k * 2103 + n];
    #pragma unroll
    for (int r = 0; r < 8; ++r) acc[r] += xs[r][k] * w;
  }
  for (int r = 0; r < 8; ++r) xp1[(size_t)(b0 + r) * 2112 + n] = acc[r];
}

__launch_bounds__(256)
__global__ void k_transpose(const float* __restrict__ W, u16* __restrict__ WT,
                            int K, int N, int Kpad, int RowsPad)
{
  int tilesN = RowsPad / 64;
  int tk = blockIdx.x / tilesN, tn = blockIdx.x % tilesN;
  int k0 = tk * 64, n0 = tn * 64;
  __shared__ u16 lds[64][72];
  int tid = threadIdx.x;
  int nl = tid & 63, q = tid >> 6;
  for (int i = 0; i < 16; ++i) {
    int kl = q * 16 + i;
    int k = k0 + kl, n = n0 + nl;
    lds[kl][nl] = (k < K && n < N) ? f2b(W[(size_t)k * N + n]) : (u16)0;
  }
  __syncthreads();
  for (int i = 0; i < 16; ++i) {
    int rl = q * 16 + i;
    WT[(size_t)(n0 + rl) * Kpad + k0 + nl] = lds[nl][rl];
  }
}

__global__ void k_maketab(unsigned int* __restrict__ tab)
{
  if (threadIdx.x != 0 || blockIdx.x != 0) return;
  for (int x = 0; x < 8; ++x) {
    for (int li = 0; li < 32; ++li) {
      unsigned v;
      if (li < 15) {            // GRU3 ksplit
        int t3 = 15 * x + li;
        v = 0xFFFF0000u | (2u << 12) | ((unsigned)(t3 & 7) << 8) | (unsigned)(t3 >> 3);
      } else if (li < 26) {     // GRU2 ksplit
        int t2 = 11 * x + (li - 15);
        v = 0xFFFF0000u | (1u << 12) | ((unsigned)(t2 & 7) << 8) | (unsigned)(t2 >> 3);
      } else if (li < 31) {     // GRU1 pairs
        int pi = 5 * x + (li - 26);
        int i0 = 2 * pi, i1 = 2 * pi + 1;
        unsigned lo = ((unsigned)(i0 & 7) << 8) | (unsigned)(i0 >> 3);
        unsigned hw = ((unsigned)(i1 & 7) << 8) | (unsigned)(i1 >> 3);
        v = lo | (hw << 16);
      } else {
        if (x < 4) {            // OUT pairs
          unsigned lo = (3u << 12) | ((unsigned)(2 * x) << 8);
          unsigned hw = (3u << 12) | ((unsigned)(2 * x + 1) << 8);
          v = lo | (hw << 16);
        } else {                // leftover GRU1 pairs
          int pi = 40 + (x - 4);
          int i0 = 2 * pi, i1 = 2 * pi + 1;
          unsigned lo = ((unsigned)(i0 & 7) << 8) | (unsigned)(i0 >> 3);
          unsigned hw = ((unsigned)(i1 & 7) << 8) | (unsigned)(i1 >> 3);
          v = lo | (hw << 16);
        }
      }
      tab[x + 8 * li] = v;
    }
  }
}

// ---------------- K=64 staging + MFMA (r9-verbatim) ----------------
static __device__ __forceinline__ void stage_gru(
    const u16* __restrict__ A, int As, const u16* __restrict__ W, int Ws, int WH,
    int r0, int j0, int kbase, int wl, int lane, char* buf)
{
  #pragma unroll
  for (int i = 0; i < 8; ++i) {
    int slot = wl * 512 + i * 64 + lane;
    const u16* g;
    if (slot < 512) {
      int row = slot >> 3, gl = slot & 7;
      int gq = gl ^ (row & 7);
      g = A + (size_t)(r0 + row) * As + kbase + gq * 8;
    } else {
      int s2 = slot - 512;
      int gate = s2 >> 9, loc = s2 & 511;
      int col = loc >> 3, gl = loc & 7;
      int gq = gl ^ (col & 7);
      g = W + ((size_t)gate * WH + j0 + col) * Ws + kbase + gq * 8;
    }
    char* l = buf + (wl * 512 + i * 64) * 16;
    GLL16(g, l);
  }
}

template<int HACC>
static __device__ __forceinline__ void mm_gru(const char* gb, int wr, int wc, int m16, int kg,
                                              f32x4 (&acc)[4][2][2])
{
  #pragma unroll
  for (int s = 0; s < 2; ++s) {
    s16x8 af[2];
    #pragma unroll
    for (int fm = 0; fm < 2; ++fm) {
      int row = wr * 32 + fm * 16 + m16;
      af[fm] = *(const s16x8*)(gb + row * 128 + DSWZ(row, s * 4 + kg));
    }
    #pragma unroll
    for (int g = 0; g < 3; ++g) {
      #pragma unroll
      for (int fn = 0; fn < 2; ++fn) {
        int col = wc * 32 + fn * 16 + m16;
        s16x8 bf = *(const s16x8*)(gb + 8192 + g * 8192 + col * 128 + DSWZ(col, s * 4 + kg));
        const int ai = (g == 2) ? HACC : g;
        #pragma unroll
        for (int fm = 0; fm < 2; ++fm)
          acc[ai][fm][fn] = __builtin_amdgcn_mfma_f32_16x16x32_bf16(af[fm], bf, acc[ai][fm][fn], 0, 0, 0);
      }
    }
  }
}

static __device__ __forceinline__ void gru_pipe(
    const u16* A0, int As0, const u16* W0, int Ws0,
    const u16* A1, int As1, const u16* W1p, int Ws1,
    int WH, int n0, int n1, int k1off,
    int r0, int j0, char* g0, char* g1, int wl, int lane,
    int wr, int wc, int m16, int kg, f32x4 (&acc)[4][2][2])
{
  const int n = n0 + n1;
#define STG(C, BUF) do { int c_ = (C); \
    if (c_ < n0) stage_gru(A0, As0, W0, Ws0, WH, r0, j0, c_ * 64, wl, lane, (BUF)); \
    else         stage_gru(A1, As1, W1p, Ws1, WH, r0, j0, (c_ - n0) * 64 + k1off, wl, lane, (BUF)); \
  } while (0)
  STG(0, g0);
  __syncthreads();
  for (int ch = 0; ch < n; ch += 2) {
    if (ch + 1 < n) STG(ch + 1, g1);
    if (ch < n0) mm_gru<2>(g0, wr, wc, m16, kg, acc);
    else         mm_gru<3>(g0, wr, wc, m16, kg, acc);
    __syncthreads();
    if (ch + 1 >= n) break;
    if (ch + 2 < n) STG(ch + 2, g0);
    if (ch + 1 < n0) mm_gru<2>(g1, wr, wc, m16, kg, acc);
    else             mm_gru<3>(g1, wr, wc, m16, kg, acc);
    __syncthreads();
  }
#undef STG
}

// ---------------- OUT tile (r9-verbatim core) ----------------
static __device__ __forceinline__ void out_tile(
    const u16* __restrict__ Ab, const u16* __restrict__ WoT, const float* __restrict__ bo,
    float* __restrict__ out, int r0, int t,
    char* g0, int ltid, int wr, int wc, int m16, int kg)
{
  f32x4 acc2[2][2];
  { f32x4 z4 = {0.f,0.f,0.f,0.f}; for (int a=0;a<2;++a) for (int b=0;b<2;++b) acc2[a][b]=z4; }
  int4 ra[2], rb2[2];
  const int n = H3P / 64;                 // 15
  #pragma unroll
  for (int it = 0; it < 2; ++it) {
    int gi = it * 256 + ltid; int r = gi >> 3, gq = gi & 7;
    ra[it]  = *(const int4*)(Ab + (size_t)(r0 + r) * H3P + gq * 8);
    rb2[it] = *(const int4*)(WoT + (size_t)r * H3P + gq * 8);
  }
  #pragma unroll
  for (int it = 0; it < 2; ++it) {
    int gi = it * 256 + ltid; int r = gi >> 3, gq = gi & 7;
    *(int4*)(g0 + r * 128 + DSWZ(r, gq)) = ra[it];
    *(int4*)(g0 + 8192 + r * 128 + DSWZ(r, gq)) = rb2[it];
  }
  __syncthreads();
  for (int ch = 0; ch < n; ++ch) {
    const bool have = (ch + 1 < n);
    if (have) {
      int kb = (ch + 1) * 64;
      #pragma unroll
      for (int it = 0; it < 2; ++it) {
        int gi = it * 256 + ltid; int r = gi >> 3, gq = gi & 7;
        ra[it]  = *(const int4*)(Ab + (size_t)(r0 + r) * H3P + kb + gq * 8);
        rb2[it] = *(const int4*)(WoT + (size_t)r * H3P + kb + gq * 8);
      }
    }
    #pragma unroll
    for (int s2 = 0; s2 < 2; ++s2) {
      s16x8 af[2], bf[2];
      #pragma unroll
      for (int fm = 0; fm < 2; ++fm) {
        int row = wr * 32 + fm * 16 + m16;
        af[fm] = *(const s16x8*)(g0 + row * 128 + DSWZ(row, s2 * 4 + kg));
      }
      #pragma unroll
      for (int fn = 0; fn < 2; ++fn) {
        int col = wc * 32 + fn * 16 + m16;
        bf[fn] = *(const s16x8*)(g0 + 8192 + col * 128 + DSWZ(col, s2 * 4 + kg));
      }
      #pragma unroll
      for (int fm = 0; fm < 2; ++fm)
        #pragma unroll
        for (int fn = 0; fn < 2; ++fn)
          acc2[fm][fn] = __builtin_amdgcn_mfma_f32_16x16x32_bf16(af[fm], bf[fn], acc2[fm][fn], 0, 0, 0);
    }
    if (have) {
      __syncthreads();
      #pragma unroll
      for (int it = 0; it < 2; ++it) {
        int gi = it * 256 + ltid; int r = gi >> 3, gq = gi & 7;
        *(int4*)(g0 + r * 128 + DSWZ(r, gq)) = ra[it];
        *(int4*)(g0 + 8192 + r * 128 + DSWZ(r, gq)) = rb2[it];
      }
      __syncthreads();
    }
  }
  __syncthreads();
  float (*ldsL)[68] = (float (*)[68])g0;
  #pragma unroll
  for (int fn = 0; fn < 2; ++fn) {
    int col = wc * 32 + fn * 16 + m16;
    float bov = (col < CH) ? bo[col] : 0.f;
    #pragma unroll
    for (int fm = 0; fm < 2; ++fm)
      #pragma unroll
      for (int ii = 0; ii < 4; ++ii)
        ldsL[wr * 32 + fm * 16 + kg * 4 + ii][col] = acc2[fm][fn][ii] + bov;
  }
  __syncthreads();
  if (ltid < 64) {
    int b = r0 + ltid;
    float mx = -1e30f;
    for (int c2 = 0; c2 < CH; ++c2) mx = fmaxf(mx, ldsL[ltid][c2]);
    float sum = 0.f;
    for (int c2 = 0; c2 < CH; ++c2) sum += expf(ldsL[ltid][c2] - mx);
    float inv = 1.f / sum;
    size_t ob = ((size_t)b * TT + t) * CH;
    for (int c2 = 0; c2 < CH; ++c2) out[ob + c2] = expf(ldsL[ltid][c2] - mx) * inv;
  }
}

// ---------------- fallback kernel: exact r9 per-step launch ----------------
__launch_bounds__(512, 2)
__global__ void k_wave9(int s, const unsigned int* __restrict__ tab,
    const u16* __restrict__ WhT1, const u16* __restrict__ WiT2, const u16* __restrict__ WhT2,
    const u16* __restrict__ WiT3, const u16* __restrict__ WhT3, const u16* __restrict__ WoT,
    const float* __restrict__ xp1,
    const float* __restrict__ gbh1,
    const float* __restrict__ gbi2, const float* __restrict__ gbh2,
    const float* __restrict__ gbi3, const float* __restrict__ gbh3,
    const float* __restrict__ bo,
    float* __restrict__ h1f, u16* __restrict__ h1b,
    float* __restrict__ h2f, u16* __restrict__ h2b,
    float* __restrict__ h3f, u16* __restrict__ h3b,
    float* __restrict__ out)
{
  extern __shared__ __align__(16) char smem[];
  const int tid  = threadIdx.x;
  const int wgrp = tid >> 8;
  const int ltid = tid & 255;
  const int lane = tid & 63;
  const int wl   = (tid >> 6) & 3;
  const int wr = wl >> 1, wc = wl & 1;
  const int m16 = lane & 15, kg = lane >> 4;
  char* g0 = smem + wgrp * 65536;
  char* g1 = g0 + 32768;

  const unsigned e  = tab[blockIdx.x];
  const unsigned lo = e & 0xFFFFu, hi = e >> 16;
  const bool ksplit = (hi == 0xFFFFu);
  const unsigned item = (!ksplit && wgrp == 1) ? hi : lo;
  const int L  = (item >> 12) & 3;
  const int rr = (item >> 8) & 0xF;
  const int cc = item & 0xFF;
  const int t = s - L;
  if (t < 0 || t >= TT) return;
  const int cur = s & 1, prv = cur ^ 1;

  if (L == 3) {
    out_tile(h3b + (size_t)prv * BB * H3P, WoT, bo, out, rr * 64, t, g0, ltid, wr, wc, m16, kg);
    return;
  }

  int H;
  const u16 *A0 = nullptr, *W0 = nullptr, *A1 = nullptr, *W1p = nullptr;
  int As0 = 0, Ws0 = 0, As1 = 0, Ws1 = 0, n0 = 0, n1 = 0, k1off = 0;
  const float *bi = nullptr, *bh;
  float *hfP, *hfC; u16 *hbC;
  if (L == 0) {
    H = HH1;
    A1 = h1b + (size_t)prv * BB * H1P; As1 = H1P; W1p = WhT1; Ws1 = H1P; n1 = 11;
    bh = gbh1;
    hfP = h1f + (size_t)prv * BB * H1P; hfC = h1f + (size_t)cur * BB * H1P;
    hbC = h1b + (size_t)cur * BB * H1P;
  } else if (L == 1) {
    H = HH1; bi = gbi2; bh = gbh2;
    hfP = h2f + (size_t)prv * BB * H1P; hfC = h2f + (size_t)cur * BB * H1P;
    hbC = h2b + (size_t)cur * BB * H1P;
    if (wgrp == 0) { A0 = h1b + (size_t)prv * BB * H1P; As0 = H1P; W0 = WiT2; Ws0 = H1P; n0 = 11; As1 = H1P; }
    else           { A1 = h2b + (size_t)prv * BB * H1P; As1 = H1P; W1p = WhT2; Ws1 = H1P; n1 = 11; }
  } else {
    H = HH3; bi = gbi3; bh = gbh3;
    hfP = h3f + (size_t)prv * BB * H3P; hfC = h3f + (size_t)cur * BB * H3P;
    hbC = h3b + (size_t)cur * BB * H3P;
    if (wgrp == 0) {
      A0 = h2b + (size_t)prv * BB * H1P; As0 = H1P; W0 = WiT3; Ws0 = H1P; n0 = 11;
      A1 = h3b + (size_t)prv * BB * H3P; As1 = H3P; W1p = WhT3; Ws1 = H3P; n1 = 2; k1off = 0;
    } else {
      A1 = h3b + (size_t)prv * BB * H3P; As1 = H3P; W1p = WhT3; Ws1 = H3P; n1 = 13; k1off = 128;
    }
  }
  const int r0 = rr * 64, j0 = cc * 64;

  f32x4 acc[4][2][2];
  { f32x4 z4 = {0.f, 0.f, 0.f, 0.f};
    for (int g = 0; g < 4; ++g) for (int a = 0; a < 2; ++a) for (int b = 0; b < 2; ++b) acc[g][a][b] = z4; }

  gru_pipe(A0, As0, W0, Ws0, A1, As1, W1p, Ws1, H, n0, n1, k1off,
           r0, j0, g0, g1, wl, lane, wr, wc, m16, kg, acc);

  if (ksplit) {
    __syncthreads();
    float* red = (float*)smem;
    if (wgrp == 1) {
      float* b = red + ltid * 64;
      #pragma unroll
      for (int g = 0; g < 4; ++g)
        #pragma unroll
        for (int fm = 0; fm < 2; ++fm)
          #pragma unroll
          for (int fn = 0; fn < 2; ++fn)
            *(f32x4*)(b + ((g * 2 + fm) * 2 + fn) * 4) = acc[g][fm][fn];
    }
    __syncthreads();
    if (wgrp == 1) return;
    {
      const float* b = red + ltid * 64;
      #pragma unroll
      for (int g = 0; g < 4; ++g)
        #pragma unroll
        for (int fm = 0; fm < 2; ++fm)
          #pragma unroll
          for (int fn = 0; fn < 2; ++fn)
            acc[g][fm][fn] += *(const f32x4*)(b + ((g * 2 + fm) * 2 + fn) * 4);
    }
  }

  #pragma unroll
  for (int fn = 0; fn < 2; ++fn) {
    int j = j0 + wc * 32 + fn * 16 + m16;
    if (j >= H) continue;
    float bhz = bh[j], bhr = bh[H + j], bhh = bh[2 * H + j];
    float biz = 0.f, bir = 0.f, bih = 0.f;
    if (L != 0) { biz = bi[j]; bir = bi[H + j]; bih = bi[2 * H + j]; }
    #pragma unroll
    for (int fm = 0; fm < 2; ++fm) {
      #pragma unroll
      for (int ii = 0; ii < 4; ++ii) {
        int row = r0 + wr * 32 + fm * 16 + kg * 4 + ii;
        float az  = acc[0][fm][fn][ii];
        float ar  = acc[1][fm][fn][ii];
        float axh = acc[2][fm][fn][ii];
        float arh = acc[3][fm][fn][ii];
        float pz, pr, xh_, rh_;
        if (L == 0) {
          const float* xr_ = xp1 + (size_t)row * 2112;
          pz  = xr_[j] + az + bhz;
          pr  = xr_[HH1 + j] + ar + bhr;
          xh_ = xr_[2 * HH1 + j];
          rh_ = arh + bhh;
        } else {
          pz  = az + biz + bhz;
          pr  = ar + bir + bhr;
          xh_ = axh + bih;
          rh_ = arh + bhh;
        }
        float zg = 1.f / (1.f + expf(-pz));
        float rg = 1.f / (1.f + expf(-pr));
        float hh = tanhf(xh_ + rg * rh_);
        float hp = hfP[(size_t)row * As1 + j];
        float hn = zg * hp + (1.f - zg) * hh;
        hfC[(size_t)row * As1 + j] = hn;
        hbC[(size_t)row * As1 + j] = f2b(hn);
      }
    }
  }
}

// ---------------- grouped persistent kernel: steps [s0,s1), ring depth R=GRP ----------------
__launch_bounds__(512)
__global__ void k_pers(int s0, int s1, int R,
    const unsigned int* __restrict__ tab, unsigned int* __restrict__ cnt,
    const u16* __restrict__ WhT1, const u16* __restrict__ WiT2, const u16* __restrict__ WhT2,
    const u16* __restrict__ WiT3, const u16* __restrict__ WhT3, const u16* __restrict__ WoT,
    const float* __restrict__ xp1,
    const float* __restrict__ gbh1,
    const float* __restrict__ gbi2, const float* __restrict__ gbh2,
    const float* __restrict__ gbi3, const float* __restrict__ gbh3,
    const float* __restrict__ bo,
    u16* __restrict__ h1r, u16* __restrict__ h2r, u16* __restrict__ h3r,
    float* __restrict__ h1f, float* __restrict__ h2f, float* __restrict__ h3f,
    float* __restrict__ out)
{
  extern __shared__ __align__(16) char smem[];
  const int tid  = threadIdx.x;
  const int wgrp = tid >> 8;
  const int ltid = tid & 255;
  const int lane = tid & 63;
  const int wl   = (tid >> 6) & 3;
  const int wr = wl >> 1, wc = wl & 1;
  const int m16 = lane & 15, kg = lane >> 4;
  char* g0 = smem + wgrp * 65536;
  char* g1 = g0 + 32768;
  u16 (*htile)[72] = (u16 (*)[72])g1;     // 64x72 u16 = 9216B, free after pipe/reduction

  const unsigned e  = tab[blockIdx.x];
  const unsigned lo = e & 0xFFFFu, hi = e >> 16;
  const bool ksplit = (hi == 0xFFFFu);
  const unsigned item = (!ksplit && wgrp == 1) ? hi : lo;
  const int L  = (item >> 12) & 3;
  const int rr = (item >> 8) & 0xF;
  const int cc = item & 0xFF;
  const int r0 = rr * 64, j0 = cc * 64;

  int H = 0, As0 = 0, Ws0 = 0, As1 = H3P, Ws1 = 0, n0 = 0, n1 = 0, k1off = 0;
  const u16 *A0base = nullptr, *W0p = nullptr, *A1base = nullptr, *W1p = nullptr;
  u16 *hbCbase = nullptr;
  float *hfbase = nullptr;
  const float *bi = nullptr, *bh = nullptr;
  bool do_epi = false;
  if (L == 0) {
    H = HH1;
    A1base = h1r; As1 = H1P; W1p = WhT1; Ws1 = H1P; n1 = 11;
    bh = gbh1; hbCbase = h1r; hfbase = h1f; do_epi = true;
  } else if (L == 1) {
    H = HH1; bi = gbi2; bh = gbh2; hbCbase = h2r; hfbase = h2f;
    As1 = H1P;
    if (wgrp == 0) { A0base = h1r; As0 = H1P; W0p = WiT2; Ws0 = H1P; n0 = 11; do_epi = true; }
    else           { A1base = h2r; W1p = WhT2; Ws1 = H1P; n1 = 11; }
  } else if (L == 2) {
    H = HH3; bi = gbi3; bh = gbh3; hbCbase = h3r; hfbase = h3f;
    As1 = H3P;
    if (wgrp == 0) {
      A0base = h2r; As0 = H1P; W0p = WiT3; Ws0 = H1P; n0 = 11;
      A1base = h3r; W1p = WhT3; Ws1 = H3P; n1 = 2; k1off = 0; do_epi = true;
    } else {
      A1base = h3r; W1p = WhT3; Ws1 = H3P; n1 = 13; k1off = 128;
    }
  }

  // ---- load hp from hf (group start) ----
  f32x4 hp_[2][2];
  { f32x4 z4 = {0.f,0.f,0.f,0.f}; for (int a=0;a<2;++a) for (int b=0;b<2;++b) hp_[a][b]=z4; }
  if (do_epi) {
    #pragma unroll
    for (int fn = 0; fn < 2; ++fn) {
      int j = j0 + wc * 32 + fn * 16 + m16;
      if (j >= H) continue;
      #pragma unroll
      for (int fm = 0; fm < 2; ++fm)
        #pragma unroll
        for (int ii = 0; ii < 4; ++ii) {
          int row = r0 + wr * 32 + fm * 16 + kg * 4 + ii;
          hp_[fn][fm][ii] = hfbase[(size_t)row * As1 + j];
        }
    }
  }

  for (int s = s0; s < s1; ++s) {
    const int t = s - L;
    const int curS = s % R, prvS = (s + R - 1) % R;

    if (t >= 0 && t < TT) {
      if (L == 3) {
        out_tile(h3r + (size_t)prvS * BB * H3P, WoT, bo, out, r0, t, g0, ltid, wr, wc, m16, kg);
      } else {
        const u16* A0 = A0base ? A0base + (size_t)prvS * BB * As0 : nullptr;
        const u16* A1 = A1base ? A1base + (size_t)prvS * BB * As1 : nullptr;

        f32x4 acc[4][2][2];
        { f32x4 z4 = {0.f,0.f,0.f,0.f};
          for (int g = 0; g < 4; ++g) for (int a = 0; a < 2; ++a) for (int b = 0; b < 2; ++b) acc[g][a][b] = z4; }

        gru_pipe(A0, As0, W0p, Ws0, A1, As1, W1p, Ws1, H, n0, n1, k1off,
                 r0, j0, g0, g1, wl, lane, wr, wc, m16, kg, acc);

        if (ksplit) {
          __syncthreads();
          float* red = (float*)smem;
          if (wgrp == 1) {
            float* b = red + ltid * 64;
            #pragma unroll
            for (int g = 0; g < 4; ++g)
              #pragma unroll
              for (int fm = 0; fm < 2; ++fm)
                #pragma unroll
                for (int fn = 0; fn < 2; ++fn)
                  *(f32x4*)(b + ((g * 2 + fm) * 2 + fn) * 4) = acc[g][fm][fn];
          }
          __syncthreads();
          if (wgrp == 0) {
            const float* b = red + ltid * 64;
            #pragma unroll
            for (int g = 0; g < 4; ++g)
              #pragma unroll
              for (int fm = 0; fm < 2; ++fm)
                #pragma unroll
                for (int fn = 0; fn < 2; ++fn)
                  acc[g][fm][fn] += *(const f32x4*)(b + ((g * 2 + fm) * 2 + fn) * 4);
          }
        }

        // red area (overlaps htile) must be fully consumed before tile writes
        __syncthreads();

        if (do_epi) {
          #pragma unroll
          for (int fn = 0; fn < 2; ++fn) {
            int j = j0 + wc * 32 + fn * 16 + m16;
            bool jv = (j < H);
            float bhz = jv ? bh[j] : 0.f, bhr = jv ? bh[H + j] : 0.f, bhh = jv ? bh[2 * H + j] : 0.f;
            float biz = 0.f, bir = 0.f, bih = 0.f;
            if (L != 0 && jv) { biz = bi[j]; bir = bi[H + j]; bih = bi[2 * H + j]; }
            #pragma unroll
            for (int fm = 0; fm < 2; ++fm) {
              #pragma unroll
              for (int ii = 0; ii < 4; ++ii) {
                int row = r0 + wr * 32 + fm * 16 + kg * 4 + ii;
                float az  = acc[0][fm][fn][ii];
                float ar  = acc[1][fm][fn][ii];
                float axh = acc[2][fm][fn][ii];
                float arh = acc[3][fm][fn][ii];
                float pz, pr, xh_, rh_;
                if (L == 0) {
                  const float* xr_ = xp1 + (size_t)row * 2112;
                  pz  = (jv ? xr_[j] : 0.f) + az + bhz;
                  pr  = (jv ? xr_[HH1 + j] : 0.f) + ar + bhr;
                  xh_ = jv ? xr_[2 * HH1 + j] : 0.f;
                  rh_ = arh + bhh;
                } else {
                  pz  = az + biz + bhz;
                  pr  = ar + bir + bhr;
                  xh_ = axh + bih;
                  rh_ = arh + bhh;
                }
                float zg = 1.f / (1.f + expf(-pz));
                float rg = 1.f / (1.f + expf(-pr));
                float hh = tanhf(xh_ + rg * rh_);
                float hn = zg * hp_[fn][fm][ii] + (1.f - zg) * hh;
                if (!jv) hn = 0.f;
                hp_[fn][fm][ii] = hn;
                htile[wr * 32 + fm * 16 + kg * 4 + ii][wc * 32 + fn * 16 + m16] = f2b(hn);
              }
            }
          }
        }

        __syncthreads();

        if (do_epi) {
          // coalesced 16B write-through of the 64x64 bf16 tile (2 stores/thread)
          u16* hbC = hbCbase + (size_t)curS * BB * As1;
          #pragma unroll
          for (int it = 0; it < 2; ++it) {
            int slot = it * 256 + ltid;      // 0..511
            int row = slot >> 3, gq = slot & 7;
            i32x4 v = *(const i32x4*)(&htile[row][gq * 8]);
            st_16_sc(&hbC[(size_t)(r0 + row) * As1 + j0 + gq * 8], v);
          }
        }
      }
    }

    // global step barrier within group (skip after last step)
    if (s + 1 < s1) {
      asm volatile("s_waitcnt vmcnt(0)" ::: "memory");
      __syncthreads();
      if (tid == 0) {
        atomicAdd(&cnt[s], 1u);
        int guard = 0;
        while (__hip_atomic_load(&cnt[s], __ATOMIC_RELAXED, __HIP_MEMORY_SCOPE_AGENT) < 256u) {
          __builtin_amdgcn_s_sleep(2);
          if (++guard > (1 << 18)) break;   // fail loud, never hang
        }
      }
      __syncthreads();
    }
  }

  // ---- store hp to hf (group end) ----
  if (do_epi) {
    #pragma unroll
    for (int fn = 0; fn < 2; ++fn) {
      int j = j0 + wc * 32 + fn * 16 + m16;
      if (j >= H) continue;
      #pragma unroll
      for (int fm = 0; fm < 2; ++fm)
        #pragma unroll
        for (int ii = 0; ii < 4; ++ii) {
          int row = r0 + wr * 32 + fm * 16 + kg * 4 + ii;
          hfbase[(size_t)row * As1 + j] = hp_[fn][fm][ii];
        }
    }
  }
}

// ---------------- host ----------------
extern "C" void kernel_launch(void* const* d_in, const int* in_sizes, int n_in,
                              void* d_out, int out_size, void* d_ws, size_t ws_size,
                              hipStream_t stream)
{
  const float* z    = (const float*)d_in[0];
  const float* W1   = (const float*)d_in[1];
  const float* b1   = (const float*)d_in[2];
  const float* gWi1 = (const float*)d_in[3];
  const float* gWh1 = (const float*)d_in[4];
  const float* gbi1 = (const float*)d_in[5];
  const float* gbh1 = (const float*)d_in[6];
  const float* gWi2 = (const float*)d_in[7];
  const float* gWh2 = (const float*)d_in[8];
  const float* gbi2 = (const float*)d_in[9];
  const float* gbh2 = (const float*)d_in[10];
  const float* gWi3 = (const float*)d_in[11];
  const float* gWh3 = (const float*)d_in[12];
  const float* gbi3 = (const float*)d_in[13];
  const float* gbh3 = (const float*)d_in[14];
  const float* Wo   = (const float*)d_in[15];
  const float* bo   = (const float*)d_in[16];

  char* ws = (char*)d_ws;
  float* x_f  = (float*)(ws + O_X);
  float* xp1  = (float*)(ws + O_XP1);
  float* h1f  = (float*)(ws + O_H1F);
  float* h2f  = (float*)(ws + O_H2F);
  float* h3f  = (float*)(ws + O_H3F);
  u16*   WhT1 = (u16*)(ws + O_WHT1);
  u16*   WiT2 = (u16*)(ws + O_WIT2);
  u16*   WhT2 = (u16*)(ws + O_WHT2);
  u16*   WiT3 = (u16*)(ws + O_WIT3);
  u16*   WhT3 = (u16*)(ws + O_WHT3);
  u16*   WoT  = (u16*)(ws + O_WOT);
  unsigned int* tab = (unsigned int*)(ws + O_TAB);
  unsigned int* cnt = (unsigned int*)(ws + O_CNT);

  (void)hipFuncSetAttribute((const void*)k_pers,
                      hipFuncAttributeMaxDynamicSharedMemorySize, 131072);
  (void)hipFuncSetAttribute((const void*)k_wave9,
                      hipFuncAttributeMaxDynamicSharedMemorySize, 131072);

  size_t avail = (ws_size > RING_BASE) ? (ws_size - RING_BASE) : 0;
  const bool big = (avail >= (size_t)GRP * SLOTALL);

  k_maketab<<<1, 64, 0, stream>>>(tab);
  k_selu<<<(BB * LAT + 255) / 256, 256, 0, stream>>>(z, W1, b1, x_f);
  k_xp1<<<9 * 64, 256, 0, stream>>>(x_f, gWi1, gbi1, xp1);

  k_transpose<<<11 * 33, 256, 0, stream>>>(gWh1, WhT1, 701, 2103, 704, 2112);
  k_transpose<<<11 * 33, 256, 0, stream>>>(gWi2, WiT2, 701, 2103, 704, 2112);
  k_transpose<<<11 * 33, 256, 0, stream>>>(gWh2, WhT2, 701, 2103, 704, 2112);
  k_transpose<<<11 * 44, 256, 0, stream>>>(gWi3, WiT3, 701, 2703, 704, 2816);
  k_transpose<<<15 * 44, 256, 0, stream>>>(gWh3, WhT3, 901, 2703, 960, 2816);
  k_transpose<<<15 * 1, 256, 0, stream>>>(Wo, WoT, 901, 35, 960, 64);

  if (big) {
    u16* h1r = (u16*)(ws + RING_BASE);
    u16* h2r = (u16*)(ws + RING_BASE + (size_t)GRP * S1B);
    u16* h3r = (u16*)(ws + RING_BASE + (size_t)GRP * S1B * 2);
    (void)hipMemsetAsync(ws + O_H1F, 0, ZERO_SMALL, stream);
    (void)hipMemsetAsync(ws + O_CNT, 0, NSTEP * 4, stream);
    (void)hipMemsetAsync((char*)h1r + (size_t)(GRP - 1) * S1B, 0, S1B, stream);
    (void)hipMemsetAsync((char*)h2r, 0, S1B, stream);
    (void)hipMemsetAsync((char*)h3r + S3B, 0, S3B, stream);
    for (int g0 = 0; g0 < NSTEP; g0 += GRP) {
      int g1 = g0 + GRP; if (g1 > NSTEP) g1 = NSTEP;
      k_pers<<<256, 512, 131072, stream>>>(g0, g1, GRP, tab, cnt,
          WhT1, WiT2, WhT2, WiT3, WhT3, WoT, xp1,
          gbh1, gbi2, gbh2, gbi3, gbh3, bo,
          h1r, h2r, h3r, h1f, h2f, h3f, (float*)d_out);
    }
  } else {
    u16* h1b = (u16*)(ws + O_H1B);
    u16* h2b = (u16*)(ws + O_H2B);
    u16* h3b = (u16*)(ws + O_H3B);
    (void)hipMemsetAsync(ws + O_H1F, 0, ZERO_SMALL, stream);
    for (int s = 0; s < NSTEP; ++s)
      k_wave9<<<256, 512, 131072, stream>>>(s, tab,
          WhT1, WiT2, WhT2, WiT3, WhT3, WoT, xp1,
          gbh1, gbi2, gbh2, gbi3, gbh3, bo,
          h1f, h1b, h2f, h2b, h3f, h3b, (float*)d_out);
  }
}

// Round 17
// 4927.920 us; speedup vs baseline: 1.5045x; 1.3179x over previous
//
#include <hip/hip_runtime.h>
#include <hip/hip_bf16.h>
#include <math.h>

typedef unsigned short u16;
typedef __attribute__((ext_vector_type(4))) float f32x4;
typedef __attribute__((ext_vector_type(8))) short s16x8;

#define BB  512
#define TT  120
#define LAT 292
#define HH1 701
#define HH3 901
#define H1P 704
#define H3P 960
#define CH  35
#define NSTEP (TT + 3)

// ws layout (bytes)
static const size_t O_X    = 0;
static const size_t O_XP1  = 598016;                // 512*2112*4 f32
static const size_t O_H1F  = 4923392;               // 2-slot f32 carry
static const size_t O_H2F  = 7806976;
static const size_t O_H3F  = 10690560;
static const size_t O_H1B  = 14622720;              // 2-slot bf16 h
static const size_t O_H2B  = 16064512;
static const size_t O_H3B  = 17506304;
static const size_t O_WHT1 = 19472384;
static const size_t O_WIT2 = 22446080;
static const size_t O_WHT2 = 25419776;
static const size_t O_WIT3 = 28393472;
static const size_t O_WHT3 = 32358400;
static const size_t O_WOT  = 37765120;
static const size_t O_TAB  = 37888000;              // 256*4
static const size_t ZERO_SMALL = 14548992;          // O_H1F..O_H3B end

#define DSWZ(row, g) ((((g) ^ ((row) & 7)) << 4))

static __device__ __forceinline__ u16 f2b(float f){
  union { float f; unsigned int i; } v; v.f = f;
  unsigned int x = v.i;
  return (u16)((x + 0x7FFFu + ((x >> 16) & 1u)) >> 16);
}

#define GLL16(g, l) __builtin_amdgcn_global_load_lds( \
    (const __attribute__((address_space(1))) unsigned int*)(g), \
    (__attribute__((address_space(3))) unsigned int*)(l), 16, 0, 0)

// ---------------- prologue kernels ----------------
__launch_bounds__(256)
__global__ void k_selu(const float* __restrict__ z, const float* __restrict__ W1,
                       const float* __restrict__ b1, float* __restrict__ x)
{
  int idx = blockIdx.x * 256 + threadIdx.x;
  if (idx >= BB * LAT) return;
  int b = idx / LAT, i = idx - b * LAT;
  float acc = b1[i];
  const float* zr = z + (size_t)b * LAT;
  for (int k = 0; k < LAT; ++k)
    acc += zr[k] * W1[k * LAT + i];
  const float alpha = 1.6732632423543772f, scale = 1.0507009873554805f;
  x[idx] = scale * (acc > 0.f ? acc : alpha * (expf(acc) - 1.f));
}

__launch_bounds__(256)
__global__ void k_xp1(const float* __restrict__ x, const float* __restrict__ Wi1,
                      const float* __restrict__ bi1, float* __restrict__ xp1)
{
  __shared__ float xs[8][LAT];
  int nb = blockIdx.x % 9, bb = blockIdx.x / 9;
  int n = nb * 256 + threadIdx.x;
  int b0 = bb * 8;
  for (int i = threadIdx.x; i < 8 * LAT; i += 256)
    xs[i / LAT][i % LAT] = x[(size_t)(b0 + i / LAT) * LAT + (i % LAT)];
  __syncthreads();
  if (n >= 2112) return;
  if (n >= 2103) { for (int r = 0; r < 8; ++r) xp1[(size_t)(b0 + r) * 2112 + n] = 0.f; return; }
  float bias = bi1[n];
  float acc[8];
  for (int r = 0; r < 8; ++r) acc[r] = bias;
  for (int k = 0; k < LAT; ++k) {
    float w = Wi1[(size_t)k * 2103 + n];
    #pragma unroll
    for (int r = 0; r < 8; ++r) acc[r] += xs[r][k] * w;
  }
  for (int r = 0; r < 8; ++r) xp1[(size_t)(b0 + r) * 2112 + n] = acc[r];
}

__launch_bounds__(256)
__global__ void k_transpose(const float* __restrict__ W, u16* __restrict__ WT,
                            int K, int N, int Kpad, int RowsPad)
{
  int tilesN = RowsPad / 64;
  int tk = blockIdx.x / tilesN, tn = blockIdx.x % tilesN;
  int k0 = tk * 64, n0 = tn * 64;
  __shared__ u16 lds[64][72];
  int tid = threadIdx.x;
  int nl = tid & 63, q = tid >> 6;
  for (int i = 0; i < 16; ++i) {
    int kl = q * 16 + i;
    int k = k0 + kl, n = n0 + nl;
    lds[kl][nl] = (k < K && n < N) ? f2b(W[(size_t)k * N + n]) : (u16)0;
  }
  __syncthreads();
  for (int i = 0; i < 16; ++i) {
    int rl = q * 16 + i;
    WT[(size_t)(n0 + rl) * Kpad + k0 + nl] = lds[nl][rl];
  }
}

// ---------------- prologue: 256 slots, LAYER-pinned to XCDs ----------------
// Cuts per-step h cold-reads: every XCD previously read h1+h2+h3; now
// XCD0-3 ~ GRU3 (h2,h3), XCD3-6 ~ GRU2 (h1,h2), XCD6-7 ~ GRU1+OUT (h1,h3).
// Item encoding identical to r9: ksplit entries (hi=0xFFFF), pair entries.
__global__ void k_maketab(unsigned int* __restrict__ tab)
{
  if (threadIdx.x != 0 || blockIdx.x != 0) return;
  int g3 = 0, g2 = 0, g1p = 0, outp = 0;
  for (int x = 0; x < 8; ++x) {
    for (int li = 0; li < 32; ++li) {
      int kind;                 // 0=G3 ksplit, 1=G2 ksplit, 2=G1 pair, 3=OUT pair
      if (x <= 2)      kind = 0;
      else if (x == 3) kind = (li < 24) ? 0 : 1;
      else if (x <= 5) kind = 1;
      else if (x == 6) kind = (li < 16) ? 1 : 2;
      else             kind = (li < 28) ? 2 : 3;
      unsigned v;
      if (kind == 0) {
        int t3 = g3++;
        v = 0xFFFF0000u | (2u << 12) | ((unsigned)(t3 & 7) << 8) | (unsigned)(t3 >> 3);
      } else if (kind == 1) {
        int t2 = g2++;
        v = 0xFFFF0000u | (1u << 12) | ((unsigned)(t2 & 7) << 8) | (unsigned)(t2 >> 3);
      } else if (kind == 2) {
        int i0 = 2 * g1p, i1 = 2 * g1p + 1; g1p++;
        unsigned lo = ((unsigned)(i0 & 7) << 8) | (unsigned)(i0 >> 3);
        unsigned hw = ((unsigned)(i1 & 7) << 8) | (unsigned)(i1 >> 3);
        v = lo | (hw << 16);
      } else {
        unsigned lo = (3u << 12) | ((unsigned)(2 * outp) << 8);
        unsigned hw = (3u << 12) | ((unsigned)(2 * outp + 1) << 8);
        outp++;
        v = lo | (hw << 16);
      }
      tab[x + 8 * li] = v;
    }
  }
}

// ---------------- K=64 staging + MFMA (r9-verbatim, proven 4983us/3.9e-3) ----------------
static __device__ __forceinline__ void stage_gru(
    const u16* __restrict__ A, int As, const u16* __restrict__ W, int Ws, int WH,
    int r0, int j0, int kbase, int wl, int lane, char* buf)
{
  #pragma unroll
  for (int i = 0; i < 8; ++i) {
    int slot = wl * 512 + i * 64 + lane;
    const u16* g;
    if (slot < 512) {
      int row = slot >> 3, gl = slot & 7;
      int gq = gl ^ (row & 7);
      g = A + (size_t)(r0 + row) * As + kbase + gq * 8;
    } else {
      int s2 = slot - 512;
      int gate = s2 >> 9, loc = s2 & 511;
      int col = loc >> 3, gl = loc & 7;
      int gq = gl ^ (col & 7);
      g = W + ((size_t)gate * WH + j0 + col) * Ws + kbase + gq * 8;
    }
    char* l = buf + (wl * 512 + i * 64) * 16;
    GLL16(g, l);
  }
}

template<int HACC>
static __device__ __forceinline__ void mm_gru(const char* gb, int wr, int wc, int m16, int kg,
                                              f32x4 (&acc)[4][2][2])
{
  #pragma unroll
  for (int s = 0; s < 2; ++s) {
    s16x8 af[2];
    #pragma unroll
    for (int fm = 0; fm < 2; ++fm) {
      int row = wr * 32 + fm * 16 + m16;
      af[fm] = *(const s16x8*)(gb + row * 128 + DSWZ(row, s * 4 + kg));
    }
    #pragma unroll
    for (int g = 0; g < 3; ++g) {
      #pragma unroll
      for (int fn = 0; fn < 2; ++fn) {
        int col = wc * 32 + fn * 16 + m16;
        s16x8 bf = *(const s16x8*)(gb + 8192 + g * 8192 + col * 128 + DSWZ(col, s * 4 + kg));
        const int ai = (g == 2) ? HACC : g;
        #pragma unroll
        for (int fm = 0; fm < 2; ++fm)
          acc[ai][fm][fn] = __builtin_amdgcn_mfma_f32_16x16x32_bf16(af[fm], bf, acc[ai][fm][fn], 0, 0, 0);
      }
    }
  }
}

static __device__ __forceinline__ void gru_pipe(
    const u16* A0, int As0, const u16* W0, int Ws0,
    const u16* A1, int As1, const u16* W1p, int Ws1,
    int WH, int n0, int n1, int k1off,
    int r0, int j0, char* g0, char* g1, int wl, int lane,
    int wr, int wc, int m16, int kg, f32x4 (&acc)[4][2][2])
{
  const int n = n0 + n1;
#define STG(C, BUF) do { int c_ = (C); \
    if (c_ < n0) stage_gru(A0, As0, W0, Ws0, WH, r0, j0, c_ * 64, wl, lane, (BUF)); \
    else         stage_gru(A1, As1, W1p, Ws1, WH, r0, j0, (c_ - n0) * 64 + k1off, wl, lane, (BUF)); \
  } while (0)
  STG(0, g0);
  __syncthreads();
  for (int ch = 0; ch < n; ch += 2) {
    if (ch + 1 < n) STG(ch + 1, g1);
    if (ch < n0) mm_gru<2>(g0, wr, wc, m16, kg, acc);
    else         mm_gru<3>(g0, wr, wc, m16, kg, acc);
    __syncthreads();
    if (ch + 1 >= n) break;
    if (ch + 2 < n) STG(ch + 2, g0);
    if (ch + 1 < n0) mm_gru<2>(g1, wr, wc, m16, kg, acc);
    else             mm_gru<3>(g1, wr, wc, m16, kg, acc);
    __syncthreads();
  }
#undef STG
}

// ---------------- OUT tile (r9-verbatim core) ----------------
static __device__ __forceinline__ void out_tile(
    const u16* __restrict__ Ab, const u16* __restrict__ WoT, const float* __restrict__ bo,
    float* __restrict__ out, int r0, int t,
    char* g0, int ltid, int wr, int wc, int m16, int kg)
{
  f32x4 acc2[2][2];
  { f32x4 z4 = {0.f,0.f,0.f,0.f}; for (int a=0;a<2;++a) for (int b=0;b<2;++b) acc2[a][b]=z4; }
  int4 ra[2], rb2[2];
  const int n = H3P / 64;                 // 15
  #pragma unroll
  for (int it = 0; it < 2; ++it) {
    int gi = it * 256 + ltid; int r = gi >> 3, gq = gi & 7;
    ra[it]  = *(const int4*)(Ab + (size_t)(r0 + r) * H3P + gq * 8);
    rb2[it] = *(const int4*)(WoT + (size_t)r * H3P + gq * 8);
  }
  #pragma unroll
  for (int it = 0; it < 2; ++it) {
    int gi = it * 256 + ltid; int r = gi >> 3, gq = gi & 7;
    *(int4*)(g0 + r * 128 + DSWZ(r, gq)) = ra[it];
    *(int4*)(g0 + 8192 + r * 128 + DSWZ(r, gq)) = rb2[it];
  }
  __syncthreads();
  for (int ch = 0; ch < n; ++ch) {
    const bool have = (ch + 1 < n);
    if (have) {
      int kb = (ch + 1) * 64;
      #pragma unroll
      for (int it = 0; it < 2; ++it) {
        int gi = it * 256 + ltid; int r = gi >> 3, gq = gi & 7;
        ra[it]  = *(const int4*)(Ab + (size_t)(r0 + r) * H3P + kb + gq * 8);
        rb2[it] = *(const int4*)(WoT + (size_t)r * H3P + kb + gq * 8);
      }
    }
    #pragma unroll
    for (int s2 = 0; s2 < 2; ++s2) {
      s16x8 af[2], bf[2];
      #pragma unroll
      for (int fm = 0; fm < 2; ++fm) {
        int row = wr * 32 + fm * 16 + m16;
        af[fm] = *(const s16x8*)(g0 + row * 128 + DSWZ(row, s2 * 4 + kg));
      }
      #pragma unroll
      for (int fn = 0; fn < 2; ++fn) {
        int col = wc * 32 + fn * 16 + m16;
        bf[fn] = *(const s16x8*)(g0 + 8192 + col * 128 + DSWZ(col, s2 * 4 + kg));
      }
      #pragma unroll
      for (int fm = 0; fm < 2; ++fm)
        #pragma unroll
        for (int fn = 0; fn < 2; ++fn)
          acc2[fm][fn] = __builtin_amdgcn_mfma_f32_16x16x32_bf16(af[fm], bf[fn], acc2[fm][fn], 0, 0, 0);
    }
    if (have) {
      __syncthreads();
      #pragma unroll
      for (int it = 0; it < 2; ++it) {
        int gi = it * 256 + ltid; int r = gi >> 3, gq = gi & 7;
        *(int4*)(g0 + r * 128 + DSWZ(r, gq)) = ra[it];
        *(int4*)(g0 + 8192 + r * 128 + DSWZ(r, gq)) = rb2[it];
      }
      __syncthreads();
    }
  }
  __syncthreads();
  float (*ldsL)[68] = (float (*)[68])g0;
  #pragma unroll
  for (int fn = 0; fn < 2; ++fn) {
    int col = wc * 32 + fn * 16 + m16;
    float bov = (col < CH) ? bo[col] : 0.f;
    #pragma unroll
    for (int fm = 0; fm < 2; ++fm)
      #pragma unroll
      for (int ii = 0; ii < 4; ++ii)
        ldsL[wr * 32 + fm * 16 + kg * 4 + ii][col] = acc2[fm][fn][ii] + bov;
  }
  __syncthreads();
  if (ltid < 64) {
    int b = r0 + ltid;
    float mx = -1e30f;
    for (int c2 = 0; c2 < CH; ++c2) mx = fmaxf(mx, ldsL[ltid][c2]);
    float sum = 0.f;
    for (int c2 = 0; c2 < CH; ++c2) sum += expf(ldsL[ltid][c2] - mx);
    float inv = 1.f / sum;
    size_t ob = ((size_t)b * TT + t) * CH;
    for (int c2 = 0; c2 < CH; ++c2) out[ob + c2] = expf(ldsL[ltid][c2] - mx) * inv;
  }
}

// ---------------- per-step kernel (r9-verbatim) ----------------
__launch_bounds__(512, 2)
__global__ void k_wave9(int s, const unsigned int* __restrict__ tab,
    const u16* __restrict__ WhT1, const u16* __restrict__ WiT2, const u16* __restrict__ WhT2,
    const u16* __restrict__ WiT3, const u16* __restrict__ WhT3, const u16* __restrict__ WoT,
    const float* __restrict__ xp1,
    const float* __restrict__ gbh1,
    const float* __restrict__ gbi2, const float* __restrict__ gbh2,
    const float* __restrict__ gbi3, const float* __restrict__ gbh3,
    const float* __restrict__ bo,
    float* __restrict__ h1f, u16* __restrict__ h1b,
    float* __restrict__ h2f, u16* __restrict__ h2b,
    float* __restrict__ h3f, u16* __restrict__ h3b,
    float* __restrict__ out)
{
  extern __shared__ __align__(16) char smem[];
  const int tid  = threadIdx.x;
  const int wgrp = tid >> 8;
  const int ltid = tid & 255;
  const int lane = tid & 63;
  const int wl   = (tid >> 6) & 3;
  const int wr = wl >> 1, wc = wl & 1;
  const int m16 = lane & 15, kg = lane >> 4;
  char* g0 = smem + wgrp * 65536;
  char* g1 = g0 + 32768;

  const unsigned e  = tab[blockIdx.x];
  const unsigned lo = e & 0xFFFFu, hi = e >> 16;
  const bool ksplit = (hi == 0xFFFFu);
  const unsigned item = (!ksplit && wgrp == 1) ? hi : lo;
  const int L  = (item >> 12) & 3;
  const int rr = (item >> 8) & 0xF;
  const int cc = item & 0xFF;
  const int t = s - L;
  if (t < 0 || t >= TT) return;
  const int cur = s & 1, prv = cur ^ 1;

  if (L == 3) {
    out_tile(h3b + (size_t)prv * BB * H3P, WoT, bo, out, rr * 64, t, g0, ltid, wr, wc, m16, kg);
    return;
  }

  int H;
  const u16 *A0 = nullptr, *W0 = nullptr, *A1 = nullptr, *W1p = nullptr;
  int As0 = 0, Ws0 = 0, As1 = 0, Ws1 = 0, n0 = 0, n1 = 0, k1off = 0;
  const float *bi = nullptr, *bh;
  float *hfP, *hfC; u16 *hbC;
  if (L == 0) {
    H = HH1;
    A1 = h1b + (size_t)prv * BB * H1P; As1 = H1P; W1p = WhT1; Ws1 = H1P; n1 = 11;
    bh = gbh1;
    hfP = h1f + (size_t)prv * BB * H1P; hfC = h1f + (size_t)cur * BB * H1P;
    hbC = h1b + (size_t)cur * BB * H1P;
  } else if (L == 1) {
    H = HH1; bi = gbi2; bh = gbh2;
    hfP = h2f + (size_t)prv * BB * H1P; hfC = h2f + (size_t)cur * BB * H1P;
    hbC = h2b + (size_t)cur * BB * H1P;
    if (wgrp == 0) { A0 = h1b + (size_t)prv * BB * H1P; As0 = H1P; W0 = WiT2; Ws0 = H1P; n0 = 11; As1 = H1P; }
    else           { A1 = h2b + (size_t)prv * BB * H1P; As1 = H1P; W1p = WhT2; Ws1 = H1P; n1 = 11; }
  } else {
    H = HH3; bi = gbi3; bh = gbh3;
    hfP = h3f + (size_t)prv * BB * H3P; hfC = h3f + (size_t)cur * BB * H3P;
    hbC = h3b + (size_t)cur * BB * H3P;
    if (wgrp == 0) {
      A0 = h2b + (size_t)prv * BB * H1P; As0 = H1P; W0 = WiT3; Ws0 = H1P; n0 = 11;
      A1 = h3b + (size_t)prv * BB * H3P; As1 = H3P; W1p = WhT3; Ws1 = H3P; n1 = 2; k1off = 0;
    } else {
      A1 = h3b + (size_t)prv * BB * H3P; As1 = H3P; W1p = WhT3; Ws1 = H3P; n1 = 13; k1off = 128;
    }
  }
  const int r0 = rr * 64, j0 = cc * 64;

  f32x4 acc[4][2][2];
  { f32x4 z4 = {0.f, 0.f, 0.f, 0.f};
    for (int g = 0; g < 4; ++g) for (int a = 0; a < 2; ++a) for (int b = 0; b < 2; ++b) acc[g][a][b] = z4; }

  gru_pipe(A0, As0, W0, Ws0, A1, As1, W1p, Ws1, H, n0, n1, k1off,
           r0, j0, g0, g1, wl, lane, wr, wc, m16, kg, acc);

  if (ksplit) {
    __syncthreads();
    float* red = (float*)smem;
    if (wgrp == 1) {
      float* b = red + ltid * 64;
      #pragma unroll
      for (int g = 0; g < 4; ++g)
        #pragma unroll
        for (int fm = 0; fm < 2; ++fm)
          #pragma unroll
          for (int fn = 0; fn < 2; ++fn)
            *(f32x4*)(b + ((g * 2 + fm) * 2 + fn) * 4) = acc[g][fm][fn];
    }
    __syncthreads();
    if (wgrp == 1) return;
    {
      const float* b = red + ltid * 64;
      #pragma unroll
      for (int g = 0; g < 4; ++g)
        #pragma unroll
        for (int fm = 0; fm < 2; ++fm)
          #pragma unroll
          for (int fn = 0; fn < 2; ++fn)
            acc[g][fm][fn] += *(const f32x4*)(b + ((g * 2 + fm) * 2 + fn) * 4);
    }
  }

  #pragma unroll
  for (int fn = 0; fn < 2; ++fn) {
    int j = j0 + wc * 32 + fn * 16 + m16;
    if (j >= H) continue;
    float bhz = bh[j], bhr = bh[H + j], bhh = bh[2 * H + j];
    float biz = 0.f, bir = 0.f, bih = 0.f;
    if (L != 0) { biz = bi[j]; bir = bi[H + j]; bih = bi[2 * H + j]; }
    #pragma unroll
    for (int fm = 0; fm < 2; ++fm) {
      #pragma unroll
      for (int ii = 0; ii < 4; ++ii) {
        int row = r0 + wr * 32 + fm * 16 + kg * 4 + ii;
        float az  = acc[0][fm][fn][ii];
        float ar  = acc[1][fm][fn][ii];
        float axh = acc[2][fm][fn][ii];
        float arh = acc[3][fm][fn][ii];
        float pz, pr, xh_, rh_;
        if (L == 0) {
          const float* xr_ = xp1 + (size_t)row * 2112;
          pz  = xr_[j] + az + bhz;
          pr  = xr_[HH1 + j] + ar + bhr;
          xh_ = xr_[2 * HH1 + j];
          rh_ = arh + bhh;
        } else {
          pz  = az + biz + bhz;
          pr  = ar + bir + bhr;
          xh_ = axh + bih;
          rh_ = arh + bhh;
        }
        float zg = 1.f / (1.f + expf(-pz));
        float rg = 1.f / (1.f + expf(-pr));
        float hh = tanhf(xh_ + rg * rh_);
        float hp = hfP[(size_t)row * As1 + j];
        float hn = zg * hp + (1.f - zg) * hh;
        hfC[(size_t)row * As1 + j] = hn;
        hbC[(size_t)row * As1 + j] = f2b(hn);
      }
    }
  }
}

// ---------------- host ----------------
extern "C" void kernel_launch(void* const* d_in, const int* in_sizes, int n_in,
                              void* d_out, int out_size, void* d_ws, size_t ws_size,
                              hipStream_t stream)
{
  const float* z    = (const float*)d_in[0];
  const float* W1   = (const float*)d_in[1];
  const float* b1   = (const float*)d_in[2];
  const float* gWi1 = (const float*)d_in[3];
  const float* gWh1 = (const float*)d_in[4];
  const float* gbi1 = (const float*)d_in[5];
  const float* gbh1 = (const float*)d_in[6];
  const float* gWi2 = (const float*)d_in[7];
  const float* gWh2 = (const float*)d_in[8];
  const float* gbi2 = (const float*)d_in[9];
  const float* gbh2 = (const float*)d_in[10];
  const float* gWi3 = (const float*)d_in[11];
  const float* gWh3 = (const float*)d_in[12];
  const float* gbi3 = (const float*)d_in[13];
  const float* gbh3 = (const float*)d_in[14];
  const float* Wo   = (const float*)d_in[15];
  const float* bo   = (const float*)d_in[16];

  char* ws = (char*)d_ws;
  float* x_f  = (float*)(ws + O_X);
  float* xp1  = (float*)(ws + O_XP1);
  float* h1f  = (float*)(ws + O_H1F);
  float* h2f  = (float*)(ws + O_H2F);
  float* h3f  = (float*)(ws + O_H3F);
  u16*   h1b  = (u16*)(ws + O_H1B);
  u16*   h2b  = (u16*)(ws + O_H2B);
  u16*   h3b  = (u16*)(ws + O_H3B);
  u16*   WhT1 = (u16*)(ws + O_WHT1);
  u16*   WiT2 = (u16*)(ws + O_WIT2);
  u16*   WhT2 = (u16*)(ws + O_WHT2);
  u16*   WiT3 = (u16*)(ws + O_WIT3);
  u16*   WhT3 = (u16*)(ws + O_WHT3);
  u16*   WoT  = (u16*)(ws + O_WOT);
  unsigned int* tab = (unsigned int*)(ws + O_TAB);

  (void)hipFuncSetAttribute((const void*)k_wave9,
                            hipFuncAttributeMaxDynamicSharedMemorySize, 131072);

  (void)hipMemsetAsync(ws + O_H1F, 0, ZERO_SMALL, stream);

  k_maketab<<<1, 64, 0, stream>>>(tab);
  k_selu<<<(BB * LAT + 255) / 256, 256, 0, stream>>>(z, W1, b1, x_f);
  k_xp1<<<9 * 64, 256, 0, stream>>>(x_f, gWi1, gbi1, xp1);

  k_transpose<<<11 * 33, 256, 0, stream>>>(gWh1, WhT1, 701, 2103, 704, 2112);
  k_transpose<<<11 * 33, 256, 0, stream>>>(gWi2, WiT2, 701, 2103, 704, 2112);
  k_transpose<<<11 * 33, 256, 0, stream>>>(gWh2, WhT2, 701, 2103, 704, 2112);
  k_transpose<<<11 * 44, 256, 0, stream>>>(gWi3, WiT3, 701, 2703, 704, 2816);
  k_transpose<<<15 * 44, 256, 0, stream>>>(gWh3, WhT3, 901, 2703, 960, 2816);
  k_transpose<<<15 * 1, 256, 0, stream>>>(Wo, WoT, 901, 35, 960, 64);

  for (int s = 0; s < NSTEP; ++s)
    k_wave9<<<256, 512, 131072, stream>>>(s, tab,
        WhT1, WiT2, WhT2, WiT3, WhT3, WoT, xp1,
        gbh1, gbi2, gbh2, gbi3, gbh3, bo,
        h1f, h1b, h2f, h2b, h3f, h3b, (float*)d_out);
}